// Round 1
// baseline (2081.120 us; speedup 1.0000x reference)
//
#include <hip/hip_runtime.h>

#define NN 50000
#define NE 800000
#define NREL 16
#define NBASE 8

// ---------------- CSR build ----------------

__global__ __launch_bounds__(256) void hist_kernel(const int* __restrict__ dstv,
                                                   int* __restrict__ cnt) {
  int i = blockIdx.x * blockDim.x + threadIdx.x;
  int stride = gridDim.x * blockDim.x;
  for (; i < NE; i += stride) atomicAdd(&cnt[dstv[i]], 1);
}

// single-block exclusive scan over cnt[0..NN) -> rowptr[0..NN], rowptr[NN]=E.
// Also re-zeros cnt so it can be reused as the scatter cursor.
__global__ __launch_bounds__(1024) void scan_kernel(int* __restrict__ cnt,
                                                    int* __restrict__ rowptr) {
  __shared__ int s[1024];
  int t = threadIdx.x;
  const int CH = (NN + 1023) / 1024;  // 49
  int begin = t * CH;
  int end = begin + CH;
  if (begin > NN) begin = NN;
  if (end > NN) end = NN;
  int sum = 0;
  for (int j = begin; j < end; ++j) sum += cnt[j];
  s[t] = sum;
  __syncthreads();
  // Hillis-Steele inclusive scan over 1024 partials
  for (int off = 1; off < 1024; off <<= 1) {
    int v = (t >= off) ? s[t - off] : 0;
    __syncthreads();
    s[t] += v;
    __syncthreads();
  }
  int run = s[t] - sum;  // exclusive prefix for this chunk
  for (int j = begin; j < end; ++j) {
    int c = cnt[j];
    rowptr[j] = run;
    run += c;
    cnt[j] = 0;
  }
  if (t == 1023) rowptr[NN] = s[1023];
}

__global__ __launch_bounds__(256) void scatter_kernel(const int* __restrict__ dstv,
                                                      const int* __restrict__ rowptr,
                                                      int* __restrict__ cursor,
                                                      int* __restrict__ eid) {
  int i = blockIdx.x * blockDim.x + threadIdx.x;
  int stride = gridDim.x * blockDim.x;
  for (; i < NE; i += stride) {
    int d = dstv[i];
    int p = atomicAdd(&cursor[d], 1);
    eid[rowptr[d] + p] = i;
  }
}

// ---------------- fused RGCN layer ----------------
// Per block: 16 dst nodes. Phase A: per-wave edge aggregation into basis space
// T[d,b,i] (i = lane), staged into LDS together with h[d] (self-loop input).
// Phase B: dense contraction X[16][576] @ [basis;loop][576][DOUT] + bias, act.

template <int DOUT>
__global__ __launch_bounds__(256) void layer_kernel(
    const float* __restrict__ h,       // [NN,64]
    const float* __restrict__ basis,   // [8,64,DOUT]
    const float* __restrict__ comp,    // [16,8]
    const float* __restrict__ loopw,   // [64,DOUT]
    const float* __restrict__ bias,    // [DOUT]
    const int* __restrict__ rowptr,
    const int* __restrict__ eid,
    const int* __restrict__ srcv,
    const int* __restrict__ etv,
    const float* __restrict__ normv,
    float* __restrict__ out,           // [NN,DOUT]
    float slope)                       // leaky-relu slope (0 => relu)
{
  __shared__ float X[16][580];  // 580 pad: float4-aligned, spreads banks for DOUT=8 reads
  __shared__ float comp_s[16][8];

  int tid = threadIdx.x;
  if (tid < 128) comp_s[tid >> 3][tid & 7] = comp[tid];
  __syncthreads();

  int wave = tid >> 6;
  int lane = tid & 63;
  int dbase = blockIdx.x * 16;

  // ---- Phase A: basis-space aggregation ----
  for (int dl4 = 0; dl4 < 4; ++dl4) {
    int dl = wave * 4 + dl4;
    int d = dbase + dl;
    float acc[8] = {0.f, 0.f, 0.f, 0.f, 0.f, 0.f, 0.f, 0.f};
    float hself = 0.f;
    if (d < NN) {
      int jb = rowptr[d];
      int je = rowptr[d + 1];
      for (int j = jb; j < je; ++j) {
        int e = eid[j];
        int s = srcv[e];
        int r = etv[e];
        float nv = normv[e];
        float hv = h[s * 64 + lane] * nv;
        const float* cr = comp_s[r];
#pragma unroll
        for (int b = 0; b < 8; ++b) acc[b] = fmaf(cr[b], hv, acc[b]);
      }
      hself = h[d * 64 + lane];
    }
#pragma unroll
    for (int b = 0; b < 8; ++b) X[dl][b * 64 + lane] = acc[b];
    X[dl][512 + lane] = hself;
  }
  __syncthreads();

  // ---- Phase B: dense contraction ----
  if (DOUT == 64) {
    int o = lane;
    int xb = wave * 4;
    float a0 = 0.f, a1 = 0.f, a2 = 0.f, a3 = 0.f;
    for (int k = 0; k < 512; k += 4) {
      float w0 = basis[(k + 0) * 64 + o];
      float w1 = basis[(k + 1) * 64 + o];
      float w2 = basis[(k + 2) * 64 + o];
      float w3 = basis[(k + 3) * 64 + o];
      float4 x0 = *(const float4*)&X[xb + 0][k];
      float4 x1 = *(const float4*)&X[xb + 1][k];
      float4 x2 = *(const float4*)&X[xb + 2][k];
      float4 x3 = *(const float4*)&X[xb + 3][k];
      a0 = fmaf(x0.x, w0, fmaf(x0.y, w1, fmaf(x0.z, w2, fmaf(x0.w, w3, a0))));
      a1 = fmaf(x1.x, w0, fmaf(x1.y, w1, fmaf(x1.z, w2, fmaf(x1.w, w3, a1))));
      a2 = fmaf(x2.x, w0, fmaf(x2.y, w1, fmaf(x2.z, w2, fmaf(x2.w, w3, a2))));
      a3 = fmaf(x3.x, w0, fmaf(x3.y, w1, fmaf(x3.z, w2, fmaf(x3.w, w3, a3))));
    }
    for (int k = 0; k < 64; k += 4) {
      float w0 = loopw[(k + 0) * 64 + o];
      float w1 = loopw[(k + 1) * 64 + o];
      float w2 = loopw[(k + 2) * 64 + o];
      float w3 = loopw[(k + 3) * 64 + o];
      float4 x0 = *(const float4*)&X[xb + 0][512 + k];
      float4 x1 = *(const float4*)&X[xb + 1][512 + k];
      float4 x2 = *(const float4*)&X[xb + 2][512 + k];
      float4 x3 = *(const float4*)&X[xb + 3][512 + k];
      a0 = fmaf(x0.x, w0, fmaf(x0.y, w1, fmaf(x0.z, w2, fmaf(x0.w, w3, a0))));
      a1 = fmaf(x1.x, w0, fmaf(x1.y, w1, fmaf(x1.z, w2, fmaf(x1.w, w3, a1))));
      a2 = fmaf(x2.x, w0, fmaf(x2.y, w1, fmaf(x2.z, w2, fmaf(x2.w, w3, a2))));
      a3 = fmaf(x3.x, w0, fmaf(x3.y, w1, fmaf(x3.z, w2, fmaf(x3.w, w3, a3))));
    }
    float b = bias[o];
    float v0 = a0 + b, v1 = a1 + b, v2 = a2 + b, v3 = a3 + b;
    v0 = v0 > 0.f ? v0 : slope * v0;
    v1 = v1 > 0.f ? v1 : slope * v1;
    v2 = v2 > 0.f ? v2 : slope * v2;
    v3 = v3 > 0.f ? v3 : slope * v3;
    int d0 = dbase + xb;
    if (d0 + 0 < NN) out[(d0 + 0) * 64 + o] = v0;
    if (d0 + 1 < NN) out[(d0 + 1) * 64 + o] = v1;
    if (d0 + 2 < NN) out[(d0 + 2) * 64 + o] = v2;
    if (d0 + 3 < NN) out[(d0 + 3) * 64 + o] = v3;
  } else {
    // DOUT == 8: 128 threads, one (dst,out) pair each
    if (tid < 128) {
      int o = tid & 7;
      int dl = tid >> 3;
      float a = 0.f;
      for (int k = 0; k < 512; k += 4) {
        float4 xv = *(const float4*)&X[dl][k];
        a = fmaf(xv.x, basis[(k + 0) * 8 + o], a);
        a = fmaf(xv.y, basis[(k + 1) * 8 + o], a);
        a = fmaf(xv.z, basis[(k + 2) * 8 + o], a);
        a = fmaf(xv.w, basis[(k + 3) * 8 + o], a);
      }
      for (int k = 0; k < 64; k += 4) {
        float4 xv = *(const float4*)&X[dl][512 + k];
        a = fmaf(xv.x, loopw[(k + 0) * 8 + o], a);
        a = fmaf(xv.y, loopw[(k + 1) * 8 + o], a);
        a = fmaf(xv.z, loopw[(k + 2) * 8 + o], a);
        a = fmaf(xv.w, loopw[(k + 3) * 8 + o], a);
      }
      float v = a + bias[o];
      v = v > 0.f ? v : slope * v;
      int d = dbase + dl;
      if (d < NN) out[d * 8 + o] = v;
    }
  }
}

// ---------------- launch ----------------

extern "C" void kernel_launch(void* const* d_in, const int* in_sizes, int n_in,
                              void* d_out, int out_size, void* d_ws, size_t ws_size,
                              hipStream_t stream) {
  const float* features = (const float*)d_in[0];
  const float* normv    = (const float*)d_in[1];
  const float* basis0   = (const float*)d_in[2];
  const float* comp0    = (const float*)d_in[3];
  const float* loop0    = (const float*)d_in[4];
  const float* bias0    = (const float*)d_in[5];
  const float* basis1   = (const float*)d_in[6];
  const float* comp1    = (const float*)d_in[7];
  const float* loop1    = (const float*)d_in[8];
  const float* bias1    = (const float*)d_in[9];
  const float* basis2   = (const float*)d_in[10];
  const float* comp2    = (const float*)d_in[11];
  const float* loop2    = (const float*)d_in[12];
  const float* bias2    = (const float*)d_in[13];
  const int* etypes     = (const int*)d_in[14];
  const int* srcv       = (const int*)d_in[15];
  const int* dstv       = (const int*)d_in[16];

  char* ws = (char*)d_ws;
  size_t off = 0;
  auto alloc = [&](size_t bytes) {
    void* p = ws + off;
    off += (bytes + 255) & ~(size_t)255;
    return p;
  };
  int* rowptr = (int*)alloc((NN + 1) * sizeof(int));
  int* cnt    = (int*)alloc(NN * sizeof(int));
  int* eid    = (int*)alloc(NE * sizeof(int));
  float* h0   = (float*)alloc((size_t)NN * 64 * sizeof(float));
  float* h1   = (float*)alloc((size_t)NN * 64 * sizeof(float));

  hipMemsetAsync(cnt, 0, NN * sizeof(int), stream);
  hist_kernel<<<1024, 256, 0, stream>>>(dstv, cnt);
  scan_kernel<<<1, 1024, 0, stream>>>(cnt, rowptr);
  scatter_kernel<<<1024, 256, 0, stream>>>(dstv, rowptr, cnt, eid);

  const int grid = (NN + 15) / 16;  // 3125
  layer_kernel<64><<<grid, 256, 0, stream>>>(features, basis0, comp0, loop0, bias0,
                                             rowptr, eid, srcv, etypes, normv, h0, 0.01f);
  layer_kernel<64><<<grid, 256, 0, stream>>>(h0, basis1, comp1, loop1, bias1,
                                             rowptr, eid, srcv, etypes, normv, h1, 0.01f);
  layer_kernel<8><<<grid, 256, 0, stream>>>(h1, basis2, comp2, loop2, bias2,
                                            rowptr, eid, srcv, etypes, normv, (float*)d_out, 0.0f);
}

// Round 2
// 1423.144 us; speedup vs baseline: 1.4623x; 1.4623x over previous
//
#include <hip/hip_runtime.h>

#define NN 50000
#define NE 800000
#define NREL 16
#define NBASE 8

// ---------------- CSR build ----------------

__global__ __launch_bounds__(256) void hist_kernel(const int* __restrict__ dstv,
                                                   int* __restrict__ cnt) {
  int i = blockIdx.x * blockDim.x + threadIdx.x;
  int stride = gridDim.x * blockDim.x;
  for (; i < NE; i += stride) atomicAdd(&cnt[dstv[i]], 1);
}

// single-block exclusive scan over cnt[0..NN) -> rowptr[0..NN], rowptr[NN]=E.
// Also re-zeros cnt so it can be reused as the scatter cursor.
__global__ __launch_bounds__(1024) void scan_kernel(int* __restrict__ cnt,
                                                    int* __restrict__ rowptr) {
  __shared__ int s[1024];
  int t = threadIdx.x;
  const int CH = (NN + 1023) / 1024;  // 49
  int begin = t * CH;
  int end = begin + CH;
  if (begin > NN) begin = NN;
  if (end > NN) end = NN;
  int sum = 0;
  for (int j = begin; j < end; ++j) sum += cnt[j];
  s[t] = sum;
  __syncthreads();
  for (int off = 1; off < 1024; off <<= 1) {
    int v = (t >= off) ? s[t - off] : 0;
    __syncthreads();
    s[t] += v;
    __syncthreads();
  }
  int run = s[t] - sum;  // exclusive prefix for this chunk
  for (int j = begin; j < end; ++j) {
    int c = cnt[j];
    rowptr[j] = run;
    run += c;
    cnt[j] = 0;
  }
  if (t == 1023) rowptr[NN] = s[1023];
}

// writes packed dst-sorted edge array: pk[slot] = (etype<<16) | src
__global__ __launch_bounds__(256) void scatter_kernel(const int* __restrict__ dstv,
                                                      const int* __restrict__ srcv,
                                                      const int* __restrict__ etv,
                                                      const int* __restrict__ rowptr,
                                                      int* __restrict__ cursor,
                                                      int* __restrict__ pk) {
  int i = blockIdx.x * blockDim.x + threadIdx.x;
  int stride = gridDim.x * blockDim.x;
  for (; i < NE; i += stride) {
    int d = dstv[i];
    int p = atomicAdd(&cursor[d], 1);
    pk[rowptr[d] + p] = (etv[i] << 16) | srcv[i];
  }
}

// ---------------- fused RGCN layer ----------------
// Per block: 16 dst nodes. Phase A: per-wave edge aggregation into basis space
// T[d,b,i] (i = lane), 4-edge unrolled for MLP, norm factored out (per-dst).
// Phase B: dense contraction X[16][576] @ [basis;loop][576][DOUT] + bias, act.

template <int DOUT>
__global__ __launch_bounds__(256, 4) void layer_kernel(
    const float* __restrict__ h,       // [NN,64]
    const float* __restrict__ basis,   // [8,64,DOUT] viewed [512,DOUT]
    const float* __restrict__ comp,    // [16,8]
    const float* __restrict__ loopw,   // [64,DOUT]
    const float* __restrict__ bias,    // [DOUT]
    const int* __restrict__ rowptr,
    const int* __restrict__ pk,        // packed (etype<<16)|src, dst-sorted
    float* __restrict__ out,           // [NN,DOUT]
    float slope)                       // leaky-relu slope (0 => relu)
{
  __shared__ float X[16][580];
  __shared__ float comp_s[16][8];

  int tid = threadIdx.x;
  if (tid < 128) comp_s[tid >> 3][tid & 7] = comp[tid];
  __syncthreads();

  int wave = tid >> 6;
  int lane = tid & 63;
  int dbase = blockIdx.x * 16;

  // ---- Phase A: basis-space aggregation ----
  for (int dl4 = 0; dl4 < 4; ++dl4) {
    int dl = wave * 4 + dl4;
    int d = dbase + dl;
    float acc[8] = {0.f, 0.f, 0.f, 0.f, 0.f, 0.f, 0.f, 0.f};
    float hself = 0.f;
    if (d < NN) {
      int jb = rowptr[d];
      int je = rowptr[d + 1];
      int deg = je - jb;
      float inv = 1.0f / (float)(deg > 1 ? deg : 1);
      int j = jb;
      for (; j + 4 <= je; j += 4) {
        int p0 = __builtin_amdgcn_readfirstlane(pk[j + 0]);
        int p1 = __builtin_amdgcn_readfirstlane(pk[j + 1]);
        int p2 = __builtin_amdgcn_readfirstlane(pk[j + 2]);
        int p3 = __builtin_amdgcn_readfirstlane(pk[j + 3]);
        float h0 = h[(p0 & 0xFFFF) * 64 + lane];
        float h1 = h[(p1 & 0xFFFF) * 64 + lane];
        float h2 = h[(p2 & 0xFFFF) * 64 + lane];
        float h3 = h[(p3 & 0xFFFF) * 64 + lane];
        const float* c0 = comp_s[p0 >> 16];
        const float* c1 = comp_s[p1 >> 16];
        const float* c2 = comp_s[p2 >> 16];
        const float* c3 = comp_s[p3 >> 16];
#pragma unroll
        for (int b = 0; b < 8; ++b) {
          acc[b] = fmaf(c0[b], h0, acc[b]);
          acc[b] = fmaf(c1[b], h1, acc[b]);
          acc[b] = fmaf(c2[b], h2, acc[b]);
          acc[b] = fmaf(c3[b], h3, acc[b]);
        }
      }
      for (; j < je; ++j) {
        int p0 = __builtin_amdgcn_readfirstlane(pk[j]);
        float h0 = h[(p0 & 0xFFFF) * 64 + lane];
        const float* c0 = comp_s[p0 >> 16];
#pragma unroll
        for (int b = 0; b < 8; ++b) acc[b] = fmaf(c0[b], h0, acc[b]);
      }
#pragma unroll
      for (int b = 0; b < 8; ++b) acc[b] *= inv;
      hself = h[d * 64 + lane];
    }
#pragma unroll
    for (int b = 0; b < 8; ++b) X[dl][b * 64 + lane] = acc[b];
    X[dl][512 + lane] = hself;
  }
  __syncthreads();

  // ---- Phase B: dense contraction ----
  if (DOUT == 64) {
    int o = lane;
    int xb = wave * 4;
    float a0 = 0.f, a1 = 0.f, a2 = 0.f, a3 = 0.f;
    for (int k = 0; k < 512; k += 4) {
      float w0 = basis[(k + 0) * 64 + o];
      float w1 = basis[(k + 1) * 64 + o];
      float w2 = basis[(k + 2) * 64 + o];
      float w3 = basis[(k + 3) * 64 + o];
      float4 x0 = *(const float4*)&X[xb + 0][k];
      float4 x1 = *(const float4*)&X[xb + 1][k];
      float4 x2 = *(const float4*)&X[xb + 2][k];
      float4 x3 = *(const float4*)&X[xb + 3][k];
      a0 = fmaf(x0.x, w0, fmaf(x0.y, w1, fmaf(x0.z, w2, fmaf(x0.w, w3, a0))));
      a1 = fmaf(x1.x, w0, fmaf(x1.y, w1, fmaf(x1.z, w2, fmaf(x1.w, w3, a1))));
      a2 = fmaf(x2.x, w0, fmaf(x2.y, w1, fmaf(x2.z, w2, fmaf(x2.w, w3, a2))));
      a3 = fmaf(x3.x, w0, fmaf(x3.y, w1, fmaf(x3.z, w2, fmaf(x3.w, w3, a3))));
    }
    for (int k = 0; k < 64; k += 4) {
      float w0 = loopw[(k + 0) * 64 + o];
      float w1 = loopw[(k + 1) * 64 + o];
      float w2 = loopw[(k + 2) * 64 + o];
      float w3 = loopw[(k + 3) * 64 + o];
      float4 x0 = *(const float4*)&X[xb + 0][512 + k];
      float4 x1 = *(const float4*)&X[xb + 1][512 + k];
      float4 x2 = *(const float4*)&X[xb + 2][512 + k];
      float4 x3 = *(const float4*)&X[xb + 3][512 + k];
      a0 = fmaf(x0.x, w0, fmaf(x0.y, w1, fmaf(x0.z, w2, fmaf(x0.w, w3, a0))));
      a1 = fmaf(x1.x, w0, fmaf(x1.y, w1, fmaf(x1.z, w2, fmaf(x1.w, w3, a1))));
      a2 = fmaf(x2.x, w0, fmaf(x2.y, w1, fmaf(x2.z, w2, fmaf(x2.w, w3, a2))));
      a3 = fmaf(x3.x, w0, fmaf(x3.y, w1, fmaf(x3.z, w2, fmaf(x3.w, w3, a3))));
    }
    float b = bias[o];
    float v0 = a0 + b, v1 = a1 + b, v2 = a2 + b, v3 = a3 + b;
    v0 = v0 > 0.f ? v0 : slope * v0;
    v1 = v1 > 0.f ? v1 : slope * v1;
    v2 = v2 > 0.f ? v2 : slope * v2;
    v3 = v3 > 0.f ? v3 : slope * v3;
    int d0 = dbase + xb;
    if (d0 + 0 < NN) out[(d0 + 0) * 64 + o] = v0;
    if (d0 + 1 < NN) out[(d0 + 1) * 64 + o] = v1;
    if (d0 + 2 < NN) out[(d0 + 2) * 64 + o] = v2;
    if (d0 + 3 < NN) out[(d0 + 3) * 64 + o] = v3;
  } else {
    // DOUT == 8: 128 threads, one (dst,out) pair each
    if (tid < 128) {
      int o = tid & 7;
      int dl = tid >> 3;
      float a = 0.f;
      for (int k = 0; k < 512; k += 4) {
        float4 xv = *(const float4*)&X[dl][k];
        a = fmaf(xv.x, basis[(k + 0) * 8 + o], a);
        a = fmaf(xv.y, basis[(k + 1) * 8 + o], a);
        a = fmaf(xv.z, basis[(k + 2) * 8 + o], a);
        a = fmaf(xv.w, basis[(k + 3) * 8 + o], a);
      }
      for (int k = 0; k < 64; k += 4) {
        float4 xv = *(const float4*)&X[dl][512 + k];
        a = fmaf(xv.x, loopw[(k + 0) * 8 + o], a);
        a = fmaf(xv.y, loopw[(k + 1) * 8 + o], a);
        a = fmaf(xv.z, loopw[(k + 2) * 8 + o], a);
        a = fmaf(xv.w, loopw[(k + 3) * 8 + o], a);
      }
      float v = a + bias[o];
      v = v > 0.f ? v : slope * v;
      int d = dbase + dl;
      if (d < NN) out[d * 8 + o] = v;
    }
  }
}

// ---------------- launch ----------------

extern "C" void kernel_launch(void* const* d_in, const int* in_sizes, int n_in,
                              void* d_out, int out_size, void* d_ws, size_t ws_size,
                              hipStream_t stream) {
  const float* features = (const float*)d_in[0];
  const float* basis0   = (const float*)d_in[2];
  const float* comp0    = (const float*)d_in[3];
  const float* loop0    = (const float*)d_in[4];
  const float* bias0    = (const float*)d_in[5];
  const float* basis1   = (const float*)d_in[6];
  const float* comp1    = (const float*)d_in[7];
  const float* loop1    = (const float*)d_in[8];
  const float* bias1    = (const float*)d_in[9];
  const float* basis2   = (const float*)d_in[10];
  const float* comp2    = (const float*)d_in[11];
  const float* loop2    = (const float*)d_in[12];
  const float* bias2    = (const float*)d_in[13];
  const int* etypes     = (const int*)d_in[14];
  const int* srcv       = (const int*)d_in[15];
  const int* dstv       = (const int*)d_in[16];

  char* ws = (char*)d_ws;
  size_t off = 0;
  auto alloc = [&](size_t bytes) {
    void* p = ws + off;
    off += (bytes + 255) & ~(size_t)255;
    return p;
  };
  int* rowptr = (int*)alloc((NN + 1) * sizeof(int));
  int* cnt    = (int*)alloc(NN * sizeof(int));
  int* pk     = (int*)alloc(NE * sizeof(int));
  float* h0   = (float*)alloc((size_t)NN * 64 * sizeof(float));
  float* h1   = (float*)alloc((size_t)NN * 64 * sizeof(float));

  hipMemsetAsync(cnt, 0, NN * sizeof(int), stream);
  hist_kernel<<<1024, 256, 0, stream>>>(dstv, cnt);
  scan_kernel<<<1, 1024, 0, stream>>>(cnt, rowptr);
  scatter_kernel<<<1024, 256, 0, stream>>>(dstv, srcv, etypes, rowptr, cnt, pk);

  const int grid = (NN + 15) / 16;  // 3125
  layer_kernel<64><<<grid, 256, 0, stream>>>(features, basis0, comp0, loop0, bias0,
                                             rowptr, pk, h0, 0.01f);
  layer_kernel<64><<<grid, 256, 0, stream>>>(h0, basis1, comp1, loop1, bias1,
                                             rowptr, pk, h1, 0.01f);
  layer_kernel<8><<<grid, 256, 0, stream>>>(h1, basis2, comp2, loop2, bias2,
                                            rowptr, pk, (float*)d_out, 0.0f);
}

// Round 3
// 1104.904 us; speedup vs baseline: 1.8835x; 1.2880x over previous
//
#include <hip/hip_runtime.h>

#define NN 50000
#define NE 800000
#define NREL 16
#define NBASE 8

// ---------------- CSR build ----------------

__global__ __launch_bounds__(256) void hist_kernel(const int* __restrict__ dstv,
                                                   int* __restrict__ cnt) {
  int i = blockIdx.x * blockDim.x + threadIdx.x;
  int stride = gridDim.x * blockDim.x;
  for (; i < NE; i += stride) atomicAdd(&cnt[dstv[i]], 1);
}

// single-block exclusive scan over cnt[0..NN) -> rowptr[0..NN], rowptr[NN]=E.
// Also re-zeros cnt so it can be reused as the scatter cursor.
__global__ __launch_bounds__(1024) void scan_kernel(int* __restrict__ cnt,
                                                    int* __restrict__ rowptr) {
  __shared__ int s[1024];
  int t = threadIdx.x;
  const int CH = (NN + 1023) / 1024;  // 49
  int begin = t * CH;
  int end = begin + CH;
  if (begin > NN) begin = NN;
  if (end > NN) end = NN;
  int sum = 0;
  for (int j = begin; j < end; ++j) sum += cnt[j];
  s[t] = sum;
  __syncthreads();
  for (int off = 1; off < 1024; off <<= 1) {
    int v = (t >= off) ? s[t - off] : 0;
    __syncthreads();
    s[t] += v;
    __syncthreads();
  }
  int run = s[t] - sum;  // exclusive prefix for this chunk
  for (int j = begin; j < end; ++j) {
    int c = cnt[j];
    rowptr[j] = run;
    run += c;
    cnt[j] = 0;
  }
  if (t == 1023) rowptr[NN] = s[1023];
}

// writes packed dst-sorted edge array: pk[slot] = (etype<<16) | src
__global__ __launch_bounds__(256) void scatter_kernel(const int* __restrict__ dstv,
                                                      const int* __restrict__ srcv,
                                                      const int* __restrict__ etv,
                                                      const int* __restrict__ rowptr,
                                                      int* __restrict__ cursor,
                                                      int* __restrict__ pk) {
  int i = blockIdx.x * blockDim.x + threadIdx.x;
  int stride = gridDim.x * blockDim.x;
  for (; i < NE; i += stride) {
    int d = dstv[i];
    int p = atomicAdd(&cursor[d], 1);
    pk[rowptr[d] + p] = (etv[i] << 16) | srcv[i];
  }
}

// ---------------- fused RGCN layer ----------------
// Per block: 16 dst nodes. Phase A: per-wave edge aggregation into basis space
// T[d,b,i] (i = lane); edge metadata is wave-uniform -> scalar loads (SGPRs),
// comp coefficients read via scalar loads from global (no LDS, no VGPR cost).
// Phase B: dense contraction X[16][576] @ [basis;loop][576][DOUT] + bias, act.

template <int DOUT>
__global__ __launch_bounds__(256, 3) void layer_kernel(
    const float* __restrict__ h,       // [NN,64]
    const float* __restrict__ basis,   // [8,64,DOUT] viewed [512,DOUT]
    const float* __restrict__ comp,    // [16,8]
    const float* __restrict__ loopw,   // [64,DOUT]
    const float* __restrict__ bias,    // [DOUT]
    const int* __restrict__ rowptr,
    const int* __restrict__ pk,        // packed (etype<<16)|src, dst-sorted
    float* __restrict__ out,           // [NN,DOUT]
    float slope)                       // leaky-relu slope (0 => relu)
{
  __shared__ float X[16][580];

  int tid = threadIdx.x;
  int wave = tid >> 6;
  int lane = tid & 63;
  int dbase = blockIdx.x * 16;

  // ---- Phase A: basis-space aggregation ----
  for (int dl4 = 0; dl4 < 4; ++dl4) {
    int dl = wave * 4 + dl4;
    int d = dbase + dl;
    float acc[8] = {0.f, 0.f, 0.f, 0.f, 0.f, 0.f, 0.f, 0.f};
    float hself = 0.f;
    if (d < NN) {
      int jb = rowptr[d];
      int je = rowptr[d + 1];
      int deg = je - jb;
      float inv = 1.0f / (float)(deg > 1 ? deg : 1);
      int j = jb;
      for (; j + 4 <= je; j += 4) {
        int4 pv = *(const int4*)(pk + j);
        int p0 = __builtin_amdgcn_readfirstlane(pv.x);
        int p1 = __builtin_amdgcn_readfirstlane(pv.y);
        int p2 = __builtin_amdgcn_readfirstlane(pv.z);
        int p3 = __builtin_amdgcn_readfirstlane(pv.w);
        float h0 = h[(p0 & 0xFFFF) * 64 + lane];
        float h1 = h[(p1 & 0xFFFF) * 64 + lane];
        float h2 = h[(p2 & 0xFFFF) * 64 + lane];
        float h3 = h[(p3 & 0xFFFF) * 64 + lane];
        const float* c0 = comp + (p0 >> 16) * 8;   // wave-uniform -> s_load
        const float* c1 = comp + (p1 >> 16) * 8;
        const float* c2 = comp + (p2 >> 16) * 8;
        const float* c3 = comp + (p3 >> 16) * 8;
#pragma unroll
        for (int b = 0; b < 8; ++b) {
          acc[b] = fmaf(c0[b], h0, acc[b]);
          acc[b] = fmaf(c1[b], h1, acc[b]);
          acc[b] = fmaf(c2[b], h2, acc[b]);
          acc[b] = fmaf(c3[b], h3, acc[b]);
        }
      }
      for (; j < je; ++j) {
        int p0 = __builtin_amdgcn_readfirstlane(pk[j]);
        float h0 = h[(p0 & 0xFFFF) * 64 + lane];
        const float* c0 = comp + (p0 >> 16) * 8;
#pragma unroll
        for (int b = 0; b < 8; ++b) acc[b] = fmaf(c0[b], h0, acc[b]);
      }
#pragma unroll
      for (int b = 0; b < 8; ++b) acc[b] *= inv;
      hself = h[d * 64 + lane];
    }
#pragma unroll
    for (int b = 0; b < 8; ++b) X[dl][b * 64 + lane] = acc[b];
    X[dl][512 + lane] = hself;
  }
  __syncthreads();

  // ---- Phase B: dense contraction ----
  if (DOUT == 64) {
    int o = lane;
    int xb = wave * 4;
    float a0 = 0.f, a1 = 0.f, a2 = 0.f, a3 = 0.f;
    for (int k = 0; k < 512; k += 4) {
      float w0 = basis[(k + 0) * 64 + o];
      float w1 = basis[(k + 1) * 64 + o];
      float w2 = basis[(k + 2) * 64 + o];
      float w3 = basis[(k + 3) * 64 + o];
      float4 x0 = *(const float4*)&X[xb + 0][k];
      float4 x1 = *(const float4*)&X[xb + 1][k];
      float4 x2 = *(const float4*)&X[xb + 2][k];
      float4 x3 = *(const float4*)&X[xb + 3][k];
      a0 = fmaf(x0.x, w0, fmaf(x0.y, w1, fmaf(x0.z, w2, fmaf(x0.w, w3, a0))));
      a1 = fmaf(x1.x, w0, fmaf(x1.y, w1, fmaf(x1.z, w2, fmaf(x1.w, w3, a1))));
      a2 = fmaf(x2.x, w0, fmaf(x2.y, w1, fmaf(x2.z, w2, fmaf(x2.w, w3, a2))));
      a3 = fmaf(x3.x, w0, fmaf(x3.y, w1, fmaf(x3.z, w2, fmaf(x3.w, w3, a3))));
    }
    for (int k = 0; k < 64; k += 4) {
      float w0 = loopw[(k + 0) * 64 + o];
      float w1 = loopw[(k + 1) * 64 + o];
      float w2 = loopw[(k + 2) * 64 + o];
      float w3 = loopw[(k + 3) * 64 + o];
      float4 x0 = *(const float4*)&X[xb + 0][512 + k];
      float4 x1 = *(const float4*)&X[xb + 1][512 + k];
      float4 x2 = *(const float4*)&X[xb + 2][512 + k];
      float4 x3 = *(const float4*)&X[xb + 3][512 + k];
      a0 = fmaf(x0.x, w0, fmaf(x0.y, w1, fmaf(x0.z, w2, fmaf(x0.w, w3, a0))));
      a1 = fmaf(x1.x, w0, fmaf(x1.y, w1, fmaf(x1.z, w2, fmaf(x1.w, w3, a1))));
      a2 = fmaf(x2.x, w0, fmaf(x2.y, w1, fmaf(x2.z, w2, fmaf(x2.w, w3, a2))));
      a3 = fmaf(x3.x, w0, fmaf(x3.y, w1, fmaf(x3.z, w2, fmaf(x3.w, w3, a3))));
    }
    float b = bias[o];
    float v0 = a0 + b, v1 = a1 + b, v2 = a2 + b, v3 = a3 + b;
    v0 = v0 > 0.f ? v0 : slope * v0;
    v1 = v1 > 0.f ? v1 : slope * v1;
    v2 = v2 > 0.f ? v2 : slope * v2;
    v3 = v3 > 0.f ? v3 : slope * v3;
    int d0 = dbase + xb;
    if (d0 + 0 < NN) out[(d0 + 0) * 64 + o] = v0;
    if (d0 + 1 < NN) out[(d0 + 1) * 64 + o] = v1;
    if (d0 + 2 < NN) out[(d0 + 2) * 64 + o] = v2;
    if (d0 + 3 < NN) out[(d0 + 3) * 64 + o] = v3;
  } else {
    // DOUT == 8: 128 threads, one (dst,out) pair each
    if (tid < 128) {
      int o = tid & 7;
      int dl = tid >> 3;
      float a = 0.f;
      for (int k = 0; k < 512; k += 4) {
        float4 xv = *(const float4*)&X[dl][k];
        a = fmaf(xv.x, basis[(k + 0) * 8 + o], a);
        a = fmaf(xv.y, basis[(k + 1) * 8 + o], a);
        a = fmaf(xv.z, basis[(k + 2) * 8 + o], a);
        a = fmaf(xv.w, basis[(k + 3) * 8 + o], a);
      }
      for (int k = 0; k < 64; k += 4) {
        float4 xv = *(const float4*)&X[dl][512 + k];
        a = fmaf(xv.x, loopw[(k + 0) * 8 + o], a);
        a = fmaf(xv.y, loopw[(k + 1) * 8 + o], a);
        a = fmaf(xv.z, loopw[(k + 2) * 8 + o], a);
        a = fmaf(xv.w, loopw[(k + 3) * 8 + o], a);
      }
      float v = a + bias[o];
      v = v > 0.f ? v : slope * v;
      int d = dbase + dl;
      if (d < NN) out[d * 8 + o] = v;
    }
  }
}

// ---------------- launch ----------------

extern "C" void kernel_launch(void* const* d_in, const int* in_sizes, int n_in,
                              void* d_out, int out_size, void* d_ws, size_t ws_size,
                              hipStream_t stream) {
  const float* features = (const float*)d_in[0];
  const float* basis0   = (const float*)d_in[2];
  const float* comp0    = (const float*)d_in[3];
  const float* loop0    = (const float*)d_in[4];
  const float* bias0    = (const float*)d_in[5];
  const float* basis1   = (const float*)d_in[6];
  const float* comp1    = (const float*)d_in[7];
  const float* loop1    = (const float*)d_in[8];
  const float* bias1    = (const float*)d_in[9];
  const float* basis2   = (const float*)d_in[10];
  const float* comp2    = (const float*)d_in[11];
  const float* loop2    = (const float*)d_in[12];
  const float* bias2    = (const float*)d_in[13];
  const int* etypes     = (const int*)d_in[14];
  const int* srcv       = (const int*)d_in[15];
  const int* dstv       = (const int*)d_in[16];

  char* ws = (char*)d_ws;
  size_t off = 0;
  auto alloc = [&](size_t bytes) {
    void* p = ws + off;
    off += (bytes + 255) & ~(size_t)255;
    return p;
  };
  int* rowptr = (int*)alloc((NN + 1) * sizeof(int));
  int* cnt    = (int*)alloc(NN * sizeof(int));
  int* pk     = (int*)alloc(NE * sizeof(int));
  float* h0   = (float*)alloc((size_t)NN * 64 * sizeof(float));
  float* h1   = (float*)alloc((size_t)NN * 64 * sizeof(float));

  hipMemsetAsync(cnt, 0, NN * sizeof(int), stream);
  hist_kernel<<<1024, 256, 0, stream>>>(dstv, cnt);
  scan_kernel<<<1, 1024, 0, stream>>>(cnt, rowptr);
  scatter_kernel<<<1024, 256, 0, stream>>>(dstv, srcv, etypes, rowptr, cnt, pk);

  const int grid = (NN + 15) / 16;  // 3125
  layer_kernel<64><<<grid, 256, 0, stream>>>(features, basis0, comp0, loop0, bias0,
                                             rowptr, pk, h0, 0.01f);
  layer_kernel<64><<<grid, 256, 0, stream>>>(h0, basis1, comp1, loop1, bias1,
                                             rowptr, pk, h1, 0.01f);
  layer_kernel<8><<<grid, 256, 0, stream>>>(h1, basis2, comp2, loop2, bias2,
                                            rowptr, pk, (float*)d_out, 0.0f);
}

// Round 4
// 706.726 us; speedup vs baseline: 2.9447x; 1.5634x over previous
//
#include <hip/hip_runtime.h>

#define NN 50000
#define NE 800000
#define PKCAP 950272   // >= NE + 3*NN, 4-aligned padded edge array capacity

// ---------------- CSR build (4-padded, dst-sorted, packed) ----------------

__global__ __launch_bounds__(256) void hist_kernel(const int* __restrict__ dstv,
                                                   int* __restrict__ cnt) {
  int i = blockIdx.x * blockDim.x + threadIdx.x;
  int stride = gridDim.x * blockDim.x;
  for (; i < NE; i += stride) atomicAdd(&cnt[dstv[i]], 1);
}

// exclusive scan of 4-padded counts -> pstart; saves true degree; re-zeros cnt.
__global__ __launch_bounds__(1024) void scan_kernel(int* __restrict__ cnt,
                                                    int* __restrict__ pstart,
                                                    int* __restrict__ degv) {
  __shared__ int s[1024];
  int t = threadIdx.x;
  const int CH = (NN + 1023) / 1024;  // 49
  int begin = t * CH, end = begin + CH;
  if (begin > NN) begin = NN;
  if (end > NN) end = NN;
  int sum = 0;
  for (int j = begin; j < end; ++j) sum += (cnt[j] + 3) & ~3;
  s[t] = sum;
  __syncthreads();
  for (int off = 1; off < 1024; off <<= 1) {
    int v = (t >= off) ? s[t - off] : 0;
    __syncthreads();
    s[t] += v;
    __syncthreads();
  }
  int run = s[t] - sum;
  for (int j = begin; j < end; ++j) {
    int c = cnt[j];
    degv[j] = c;
    pstart[j] = run;
    run += (c + 3) & ~3;
    cnt[j] = 0;
  }
  if (t == 1023) pstart[NN] = s[1023];
}

// fill pk with sentinel (etype=16 -> comp_pad row of zeros, src=0)
__global__ __launch_bounds__(256) void fillpk_kernel(int* __restrict__ pk) {
  int i = blockIdx.x * 256 + threadIdx.x;
  if (i < PKCAP) pk[i] = (16 << 16);
}

__global__ __launch_bounds__(256) void scatter_kernel(const int* __restrict__ dstv,
                                                      const int* __restrict__ srcv,
                                                      const int* __restrict__ etv,
                                                      const int* __restrict__ pstart,
                                                      int* __restrict__ cursor,
                                                      int* __restrict__ pk) {
  int i = blockIdx.x * blockDim.x + threadIdx.x;
  int stride = gridDim.x * blockDim.x;
  for (; i < NE; i += stride) {
    int d = dstv[i];
    int p = atomicAdd(&cursor[d], 1);
    pk[pstart[d] + p] = (etv[i] << 16) | srcv[i];
  }
}

// comp_pad[3][17][8]: per-layer comp with an extra zero row for the sentinel
__global__ __launch_bounds__(512) void cpad_kernel(const float* __restrict__ c0,
                                                   const float* __restrict__ c1,
                                                   const float* __restrict__ c2,
                                                   float* __restrict__ cp) {
  int t = threadIdx.x;
  if (t < 408) {
    int l = t / 136, k = t % 136;
    const float* src = (l == 0) ? c0 : ((l == 1) ? c1 : c2);
    cp[t] = (k < 128) ? src[k] : 0.f;
  }
}

// ---------------- Phase A: per-dst basis-space aggregation ----------------
// One dst per wave (lane = feature). Branch-free aligned int4 edge walk with
// next-group prefetch. Writes T row [576]: cols 0..511 = aggregated basis
// coords (deg-normalized), cols 512..575 = copy of h[d] (self-loop input).

__global__ __launch_bounds__(256) void agg_kernel(
    const float* __restrict__ h,       // [NN,64]
    const float* __restrict__ cpad,    // [17,8] for this layer
    const int* __restrict__ pstart,
    const int* __restrict__ degv,
    const int* __restrict__ pk,
    float* __restrict__ T,             // [rows,576], chunk-local
    int c0, int c1)
{
  int lane = threadIdx.x & 63;
  int d = __builtin_amdgcn_readfirstlane(c0 + ((blockIdx.x * 256 + threadIdx.x) >> 6));
  if (d >= c1) return;
  int deg = degv[d];
  int ng = (deg + 3) >> 2;
  const int4* p4 = (const int4*)(pk + pstart[d]);

  float acc[8] = {0.f, 0.f, 0.f, 0.f, 0.f, 0.f, 0.f, 0.f};
  if (ng > 0) {
    int4 pv = p4[0];
    for (int g = 0; g < ng; ++g) {
      int4 nv = pv;
      if (g + 1 < ng) nv = p4[g + 1];  // prefetch next group
      {
        int pe = pv.x;
        float hv = h[(pe & 0xFFFF) * 64 + lane];
        const float* c = cpad + (pe >> 16) * 8;
#pragma unroll
        for (int b = 0; b < 8; ++b) acc[b] = fmaf(c[b], hv, acc[b]);
      }
      {
        int pe = pv.y;
        float hv = h[(pe & 0xFFFF) * 64 + lane];
        const float* c = cpad + (pe >> 16) * 8;
#pragma unroll
        for (int b = 0; b < 8; ++b) acc[b] = fmaf(c[b], hv, acc[b]);
      }
      {
        int pe = pv.z;
        float hv = h[(pe & 0xFFFF) * 64 + lane];
        const float* c = cpad + (pe >> 16) * 8;
#pragma unroll
        for (int b = 0; b < 8; ++b) acc[b] = fmaf(c[b], hv, acc[b]);
      }
      {
        int pe = pv.w;
        float hv = h[(pe & 0xFFFF) * 64 + lane];
        const float* c = cpad + (pe >> 16) * 8;
#pragma unroll
        for (int b = 0; b < 8; ++b) acc[b] = fmaf(c[b], hv, acc[b]);
      }
      pv = nv;
    }
  }
  float inv = 1.0f / (float)(deg > 1 ? deg : 1);
  float* Trow = T + (size_t)(d - c0) * 576;
#pragma unroll
  for (int b = 0; b < 8; ++b) Trow[b * 64 + lane] = acc[b] * inv;
  Trow[512 + lane] = h[(size_t)d * 64 + lane];
}

// ---------------- Phase B: dense [16 rows][576] @ [576][DOUT] ----------------

template <int DOUT>
__global__ __launch_bounds__(256) void dense_kernel(
    const float* __restrict__ T,       // [rows,576], chunk-local
    const float* __restrict__ basis,   // [512,DOUT]
    const float* __restrict__ loopw,   // [64,DOUT]
    const float* __restrict__ bias,    // [DOUT]
    float* __restrict__ out,           // [NN,DOUT]
    int c0, int c1, float slope)
{
  __shared__ float X[16][580];
  int tid = threadIdx.x;
  int dbase = c0 + blockIdx.x * 16;

  // stage 16 rows x 576 floats (144 float4 each; 16 threads per row, 9 iters)
  {
    int r = tid >> 4, i = tid & 15;
    int d = dbase + r;
    if (d < c1) {
      const float4* Tr = (const float4*)(T + (size_t)(d - c0) * 576);
#pragma unroll
      for (int q = 0; q < 9; ++q) {
        int pos = i + q * 16;
        *(float4*)&X[r][pos * 4] = Tr[pos];
      }
    } else {
#pragma unroll
      for (int q = 0; q < 9; ++q) {
        int pos = i + q * 16;
        *(float4*)&X[r][pos * 4] = float4{0.f, 0.f, 0.f, 0.f};
      }
    }
  }
  __syncthreads();

  int wave = tid >> 6;
  int lane = tid & 63;

  if (DOUT == 64) {
    int o = lane;
    int xb = wave * 4;
    float a0 = 0.f, a1 = 0.f, a2 = 0.f, a3 = 0.f;
    for (int k = 0; k < 512; k += 4) {
      float w0 = basis[(k + 0) * 64 + o];
      float w1 = basis[(k + 1) * 64 + o];
      float w2 = basis[(k + 2) * 64 + o];
      float w3 = basis[(k + 3) * 64 + o];
      float4 x0 = *(const float4*)&X[xb + 0][k];
      float4 x1 = *(const float4*)&X[xb + 1][k];
      float4 x2 = *(const float4*)&X[xb + 2][k];
      float4 x3 = *(const float4*)&X[xb + 3][k];
      a0 = fmaf(x0.x, w0, fmaf(x0.y, w1, fmaf(x0.z, w2, fmaf(x0.w, w3, a0))));
      a1 = fmaf(x1.x, w0, fmaf(x1.y, w1, fmaf(x1.z, w2, fmaf(x1.w, w3, a1))));
      a2 = fmaf(x2.x, w0, fmaf(x2.y, w1, fmaf(x2.z, w2, fmaf(x2.w, w3, a2))));
      a3 = fmaf(x3.x, w0, fmaf(x3.y, w1, fmaf(x3.z, w2, fmaf(x3.w, w3, a3))));
    }
    for (int k = 0; k < 64; k += 4) {
      float w0 = loopw[(k + 0) * 64 + o];
      float w1 = loopw[(k + 1) * 64 + o];
      float w2 = loopw[(k + 2) * 64 + o];
      float w3 = loopw[(k + 3) * 64 + o];
      float4 x0 = *(const float4*)&X[xb + 0][512 + k];
      float4 x1 = *(const float4*)&X[xb + 1][512 + k];
      float4 x2 = *(const float4*)&X[xb + 2][512 + k];
      float4 x3 = *(const float4*)&X[xb + 3][512 + k];
      a0 = fmaf(x0.x, w0, fmaf(x0.y, w1, fmaf(x0.z, w2, fmaf(x0.w, w3, a0))));
      a1 = fmaf(x1.x, w0, fmaf(x1.y, w1, fmaf(x1.z, w2, fmaf(x1.w, w3, a1))));
      a2 = fmaf(x2.x, w0, fmaf(x2.y, w1, fmaf(x2.z, w2, fmaf(x2.w, w3, a2))));
      a3 = fmaf(x3.x, w0, fmaf(x3.y, w1, fmaf(x3.z, w2, fmaf(x3.w, w3, a3))));
    }
    float b = bias[o];
    float v0 = a0 + b, v1 = a1 + b, v2 = a2 + b, v3 = a3 + b;
    v0 = v0 > 0.f ? v0 : slope * v0;
    v1 = v1 > 0.f ? v1 : slope * v1;
    v2 = v2 > 0.f ? v2 : slope * v2;
    v3 = v3 > 0.f ? v3 : slope * v3;
    int d0 = dbase + xb;
    if (d0 + 0 < c1) out[(size_t)(d0 + 0) * 64 + o] = v0;
    if (d0 + 1 < c1) out[(size_t)(d0 + 1) * 64 + o] = v1;
    if (d0 + 2 < c1) out[(size_t)(d0 + 2) * 64 + o] = v2;
    if (d0 + 3 < c1) out[(size_t)(d0 + 3) * 64 + o] = v3;
  } else {
    if (tid < 128) {
      int o = tid & 7;
      int dl = tid >> 3;
      float a = 0.f;
      for (int k = 0; k < 512; k += 4) {
        float4 xv = *(const float4*)&X[dl][k];
        a = fmaf(xv.x, basis[(k + 0) * 8 + o], a);
        a = fmaf(xv.y, basis[(k + 1) * 8 + o], a);
        a = fmaf(xv.z, basis[(k + 2) * 8 + o], a);
        a = fmaf(xv.w, basis[(k + 3) * 8 + o], a);
      }
      for (int k = 0; k < 64; k += 4) {
        float4 xv = *(const float4*)&X[dl][512 + k];
        a = fmaf(xv.x, loopw[(k + 0) * 8 + o], a);
        a = fmaf(xv.y, loopw[(k + 1) * 8 + o], a);
        a = fmaf(xv.z, loopw[(k + 2) * 8 + o], a);
        a = fmaf(xv.w, loopw[(k + 3) * 8 + o], a);
      }
      float v = a + bias[o];
      v = v > 0.f ? v : slope * v;
      int d = dbase + dl;
      if (d < c1) out[(size_t)d * 8 + o] = v;
    }
  }
}

// ---------------- launch ----------------

extern "C" void kernel_launch(void* const* d_in, const int* in_sizes, int n_in,
                              void* d_out, int out_size, void* d_ws, size_t ws_size,
                              hipStream_t stream) {
  const float* features = (const float*)d_in[0];
  const float* basis0   = (const float*)d_in[2];
  const float* comp0    = (const float*)d_in[3];
  const float* loop0    = (const float*)d_in[4];
  const float* bias0    = (const float*)d_in[5];
  const float* basis1   = (const float*)d_in[6];
  const float* comp1    = (const float*)d_in[7];
  const float* loop1    = (const float*)d_in[8];
  const float* bias1    = (const float*)d_in[9];
  const float* basis2   = (const float*)d_in[10];
  const float* comp2    = (const float*)d_in[11];
  const float* loop2    = (const float*)d_in[12];
  const float* bias2    = (const float*)d_in[13];
  const int* etypes     = (const int*)d_in[14];
  const int* srcv       = (const int*)d_in[15];
  const int* dstv       = (const int*)d_in[16];

  char* ws = (char*)d_ws;
  size_t off = 0;
  auto alloc = [&](size_t bytes) {
    void* p = ws + off;
    off += (bytes + 255) & ~(size_t)255;
    return p;
  };
  int* pstart   = (int*)alloc((NN + 1) * sizeof(int));
  int* degv     = (int*)alloc(NN * sizeof(int));
  int* cnt      = (int*)alloc(NN * sizeof(int));
  int* pk       = (int*)alloc((size_t)PKCAP * sizeof(int));
  float* cpad   = (float*)alloc(3 * 136 * sizeof(float));
  float* hbuf   = (float*)alloc((size_t)NN * 64 * sizeof(float));
  size_t fixed = off;

  // T chunk sizing from remaining workspace (576 f32 per row)
  long long avail = (long long)ws_size - (long long)fixed;
  int chunk = (int)(avail / (576 * 4));
  if (chunk > NN) chunk = NN;
  if (chunk < 256) chunk = 256;  // last-ditch; R3 proved >=30 MB exists
  float* T = (float*)alloc((size_t)chunk * 576 * sizeof(float));

  // ---- CSR build ----
  hipMemsetAsync(cnt, 0, NN * sizeof(int), stream);
  hist_kernel<<<1024, 256, 0, stream>>>(dstv, cnt);
  scan_kernel<<<1, 1024, 0, stream>>>(cnt, pstart, degv);
  fillpk_kernel<<<(PKCAP + 255) / 256, 256, 0, stream>>>(pk);
  scatter_kernel<<<1024, 256, 0, stream>>>(dstv, srcv, etypes, pstart, cnt, pk);
  cpad_kernel<<<1, 512, 0, stream>>>(comp0, comp1, comp2, cpad);

  // ---- 3 layers, chunked over dst rows ----
  const float* basis_l[3] = {basis0, basis1, basis2};
  const float* loop_l[3]  = {loop0, loop1, loop2};
  const float* bias_l[3]  = {bias0, bias1, bias2};
  const float* in_l[3]    = {features, hbuf, hbuf};
  float* out_l[3]         = {hbuf, hbuf, (float*)d_out};
  const float slope_l[3]  = {0.01f, 0.01f, 0.0f};

  for (int l = 0; l < 3; ++l) {
    for (int c0 = 0; c0 < NN; c0 += chunk) {
      int c1 = c0 + chunk;
      if (c1 > NN) c1 = NN;
      int rows = c1 - c0;
      int gridA = (rows + 3) / 4;    // 1 dst per wave, 4 waves per block
      int gridB = (rows + 15) / 16;  // 16 dst rows per block
      agg_kernel<<<gridA, 256, 0, stream>>>(in_l[l], cpad + l * 136, pstart, degv,
                                            pk, T, c0, c1);
      if (l < 2) {
        dense_kernel<64><<<gridB, 256, 0, stream>>>(T, basis_l[l], loop_l[l], bias_l[l],
                                                    out_l[l], c0, c1, slope_l[l]);
      } else {
        dense_kernel<8><<<gridB, 256, 0, stream>>>(T, basis_l[l], loop_l[l], bias_l[l],
                                                   out_l[l], c0, c1, slope_l[l]);
      }
    }
  }
}

// Round 5
// 409.258 us; speedup vs baseline: 5.0851x; 1.7268x over previous
//
#include <hip/hip_runtime.h>

#define NN 50000
#define NE 800000
#define PKCAP 950272   // >= NE + 3*NN, 4-aligned padded edge array capacity
#define KC 72          // 576/8 k-chunks

typedef __bf16 bf16x8 __attribute__((ext_vector_type(8)));
typedef float f32x4 __attribute__((ext_vector_type(4)));
typedef unsigned short ushort;
typedef unsigned int uint;

__device__ inline ushort f2bf(float x) {  // RNE float->bf16
  uint u = __builtin_bit_cast(uint, x);
  u += 0x7FFF + ((u >> 16) & 1);
  return (ushort)(u >> 16);
}

// ---------------- CSR build (4-padded, dst-sorted, packed) ----------------

__global__ __launch_bounds__(256) void hist_kernel(const int* __restrict__ dstv,
                                                   int* __restrict__ cnt) {
  int i = blockIdx.x * blockDim.x + threadIdx.x;
  int stride = gridDim.x * blockDim.x;
  for (; i < NE; i += stride) atomicAdd(&cnt[dstv[i]], 1);
}

__global__ __launch_bounds__(1024) void scan_kernel(int* __restrict__ cnt,
                                                    int* __restrict__ pstart,
                                                    int* __restrict__ degv) {
  __shared__ int s[1024];
  int t = threadIdx.x;
  const int CH = (NN + 1023) / 1024;  // 49
  int begin = t * CH, end = begin + CH;
  if (begin > NN) begin = NN;
  if (end > NN) end = NN;
  int sum = 0;
  for (int j = begin; j < end; ++j) sum += (cnt[j] + 3) & ~3;
  s[t] = sum;
  __syncthreads();
  for (int off = 1; off < 1024; off <<= 1) {
    int v = (t >= off) ? s[t - off] : 0;
    __syncthreads();
    s[t] += v;
    __syncthreads();
  }
  int run = s[t] - sum;
  for (int j = begin; j < end; ++j) {
    int c = cnt[j];
    degv[j] = c;
    pstart[j] = run;
    run += (c + 3) & ~3;
    cnt[j] = 0;
  }
  if (t == 1023) pstart[NN] = s[1023];
}

__global__ __launch_bounds__(256) void fillpk_kernel(int* __restrict__ pk) {
  int i = blockIdx.x * 256 + threadIdx.x;
  if (i < PKCAP) pk[i] = (16 << 16);  // sentinel: etype 16 (zero comp row)
}

__global__ __launch_bounds__(256) void scatter_kernel(const int* __restrict__ dstv,
                                                      const int* __restrict__ srcv,
                                                      const int* __restrict__ etv,
                                                      const int* __restrict__ pstart,
                                                      int* __restrict__ cursor,
                                                      int* __restrict__ pk) {
  int i = blockIdx.x * blockDim.x + threadIdx.x;
  int stride = gridDim.x * blockDim.x;
  for (; i < NE; i += stride) {
    int d = dstv[i];
    int p = atomicAdd(&cursor[d], 1);
    pk[pstart[d] + p] = (etv[i] << 16) | srcv[i];
  }
}

// comp_pad[3][17][8]: per-layer comp with an extra zero row for the sentinel
__global__ __launch_bounds__(512) void cpad_kernel(const float* __restrict__ c0,
                                                   const float* __restrict__ c1,
                                                   const float* __restrict__ c2,
                                                   float* __restrict__ cp) {
  int t = threadIdx.x;
  if (t < 408) {
    int l = t / 136, k = t % 136;
    const float* src = (l == 0) ? c0 : ((l == 1) ? c1 : c2);
    cp[t] = (k < 128) ? src[k] : 0.f;
  }
}

// pack [basis;loop] (576 x DOUT) into chunked bf16 W2[KC][NCOLS][8]
__global__ __launch_bounds__(256) void wprep_kernel(const float* __restrict__ basis,
                                                    const float* __restrict__ loopw,
                                                    ushort* __restrict__ W2,
                                                    int DOUT, int NCOLS) {
  int idx = blockIdx.x * 256 + threadIdx.x;
  int total = KC * NCOLS * 8;
  if (idx >= total) return;
  int j = idx & 7;
  int n = (idx >> 3) % NCOLS;
  int kc = idx / (8 * NCOLS);
  int k = kc * 8 + j;
  float v = 0.f;
  if (n < DOUT) v = (k < 512) ? basis[k * DOUT + n] : loopw[(k - 512) * DOUT + n];
  W2[((size_t)kc * NCOLS + n) * 8 + j] = f2bf(v);
}

// ---------------- Phase A: per-dst basis-space aggregation ----------------
// One dst per wave (lane = feature). Branch-free aligned int4 edge walk with
// next-group prefetch. Writes chunked bf16 T2[kc][mloc][8]: kc 0..63 =
// deg-normalized basis coords, kc 64..71 = copy of h[d] (self-loop input).

__global__ __launch_bounds__(256) void agg_kernel(
    const float* __restrict__ h,       // [NN,64]
    const float* __restrict__ cpad,    // [17,8] for this layer
    const int* __restrict__ pstart,
    const int* __restrict__ degv,
    const int* __restrict__ pk,
    ushort* __restrict__ T2,           // [KC][chunk][8] bf16
    int c0, int c1, int chunk)
{
  int lane = threadIdx.x & 63;
  int d = __builtin_amdgcn_readfirstlane(c0 + ((blockIdx.x * 256 + threadIdx.x) >> 6));
  if (d >= c1) return;
  int deg = degv[d];
  int ng = (deg + 3) >> 2;
  const int4* p4 = (const int4*)(pk + pstart[d]);

  float acc[8] = {0.f, 0.f, 0.f, 0.f, 0.f, 0.f, 0.f, 0.f};
  if (ng > 0) {
    int4 pv = p4[0];
    for (int g = 0; g < ng; ++g) {
      int4 nv = pv;
      if (g + 1 < ng) nv = p4[g + 1];  // prefetch next group
      {
        int pe = pv.x;
        float hv = h[(pe & 0xFFFF) * 64 + lane];
        const float* c = cpad + (pe >> 16) * 8;
#pragma unroll
        for (int b = 0; b < 8; ++b) acc[b] = fmaf(c[b], hv, acc[b]);
      }
      {
        int pe = pv.y;
        float hv = h[(pe & 0xFFFF) * 64 + lane];
        const float* c = cpad + (pe >> 16) * 8;
#pragma unroll
        for (int b = 0; b < 8; ++b) acc[b] = fmaf(c[b], hv, acc[b]);
      }
      {
        int pe = pv.z;
        float hv = h[(pe & 0xFFFF) * 64 + lane];
        const float* c = cpad + (pe >> 16) * 8;
#pragma unroll
        for (int b = 0; b < 8; ++b) acc[b] = fmaf(c[b], hv, acc[b]);
      }
      {
        int pe = pv.w;
        float hv = h[(pe & 0xFFFF) * 64 + lane];
        const float* c = cpad + (pe >> 16) * 8;
#pragma unroll
        for (int b = 0; b < 8; ++b) acc[b] = fmaf(c[b], hv, acc[b]);
      }
      pv = nv;
    }
  }
  float inv = 1.0f / (float)(deg > 1 ? deg : 1);
  int mloc = d - c0;
  int jj = lane & 7;
  int csub = lane >> 3;  // which 8-elem chunk within the 64-feature group
#pragma unroll
  for (int b = 0; b < 8; ++b) {
    int kc = b * 8 + csub;
    T2[((size_t)kc * chunk + mloc) * 8 + jj] = f2bf(acc[b] * inv);
  }
  float hs = h[(size_t)d * 64 + lane];
  T2[((size_t)(64 + csub) * chunk + mloc) * 8 + jj] = f2bf(hs);
}

// ---------------- Phase B: MFMA dense  out[m][n] = T[m] . Wcat[:,n] ----------
// Swapped operands: D = A*B with A[i=n][k] = Wcat[k][n], B[k][j=m] = T[m][k].
// A-frag: lane reads W2[kc][n=nt*16+(l&15)][0..8)   (16B, coalesced over lanes)
// B-frag: lane reads T2[kc][mbase+(l&15)][0..8)     (16B, coalesced over lanes)
// kc = ks*4 + (l>>4).  D: lane holds n=(l>>4)*4+reg, m=mbase+(l&15).

template <int NT, int NCOLS, int DOUT>
__global__ __launch_bounds__(256) void dense_mfma_kernel(
    const ushort* __restrict__ T2,     // [KC][chunk][8] bf16
    const ushort* __restrict__ W2,     // [KC][NCOLS][8] bf16
    const float* __restrict__ bias,    // [DOUT]
    float* __restrict__ out,           // [NN,DOUT]
    int c0, int c1, int chunk, float slope)
{
  int tid = threadIdx.x;
  int gw = blockIdx.x * 4 + (tid >> 6);   // global wave id = m-tile id
  int rows = c1 - c0;
  int mbase = gw * 16;
  if (mbase >= rows) return;
  int l = tid & 63;
  int q = l >> 4;    // k-chunk select / n-reg group
  int r = l & 15;    // A: n within tile; B: m within tile; D: m within tile

  f32x4 acc[NT];
#pragma unroll
  for (int nt = 0; nt < NT; ++nt) acc[nt] = f32x4{0.f, 0.f, 0.f, 0.f};

#pragma unroll 2
  for (int ks = 0; ks < 18; ++ks) {
    int kc = ks * 4 + q;
    bf16x8 bfrag = *(const bf16x8*)(T2 + ((size_t)kc * chunk + mbase + r) * 8);
#pragma unroll
    for (int nt = 0; nt < NT; ++nt) {
      bf16x8 afrag = *(const bf16x8*)(W2 + ((size_t)kc * NCOLS + nt * 16 + r) * 8);
      acc[nt] = __builtin_amdgcn_mfma_f32_16x16x32_bf16(afrag, bfrag, acc[nt], 0, 0, 0);
    }
  }

  int m = c0 + mbase + r;
  if (m >= c1) return;
#pragma unroll
  for (int nt = 0; nt < NT; ++nt) {
    int nb = nt * 16 + q * 4;
    if (nb < DOUT) {
      float4 bv = *(const float4*)(bias + nb);
      float v0 = acc[nt][0] + bv.x;
      float v1 = acc[nt][1] + bv.y;
      float v2 = acc[nt][2] + bv.z;
      float v3 = acc[nt][3] + bv.w;
      v0 = v0 > 0.f ? v0 : slope * v0;
      v1 = v1 > 0.f ? v1 : slope * v1;
      v2 = v2 > 0.f ? v2 : slope * v2;
      v3 = v3 > 0.f ? v3 : slope * v3;
      *(float4*)(out + (size_t)m * DOUT + nb) = float4{v0, v1, v2, v3};
    }
  }
}

// ---------------- launch ----------------

extern "C" void kernel_launch(void* const* d_in, const int* in_sizes, int n_in,
                              void* d_out, int out_size, void* d_ws, size_t ws_size,
                              hipStream_t stream) {
  const float* features = (const float*)d_in[0];
  const float* basis0   = (const float*)d_in[2];
  const float* comp0    = (const float*)d_in[3];
  const float* loop0    = (const float*)d_in[4];
  const float* bias0    = (const float*)d_in[5];
  const float* basis1   = (const float*)d_in[6];
  const float* comp1    = (const float*)d_in[7];
  const float* loop1    = (const float*)d_in[8];
  const float* bias1    = (const float*)d_in[9];
  const float* basis2   = (const float*)d_in[10];
  const float* comp2    = (const float*)d_in[11];
  const float* loop2    = (const float*)d_in[12];
  const float* bias2    = (const float*)d_in[13];
  const int* etypes     = (const int*)d_in[14];
  const int* srcv       = (const int*)d_in[15];
  const int* dstv       = (const int*)d_in[16];

  char* ws = (char*)d_ws;
  size_t off = 0;
  auto alloc = [&](size_t bytes) {
    void* p = ws + off;
    off += (bytes + 255) & ~(size_t)255;
    return p;
  };
  int* pstart   = (int*)alloc((NN + 1) * sizeof(int));
  int* degv     = (int*)alloc(NN * sizeof(int));
  int* cnt      = (int*)alloc(NN * sizeof(int));
  int* pk       = (int*)alloc((size_t)PKCAP * sizeof(int));
  float* cpad   = (float*)alloc(3 * 136 * sizeof(float));
  ushort* W2_0  = (ushort*)alloc((size_t)KC * 64 * 8 * sizeof(ushort));
  ushort* W2_1  = (ushort*)alloc((size_t)KC * 64 * 8 * sizeof(ushort));
  ushort* W2_2  = (ushort*)alloc((size_t)KC * 16 * 8 * sizeof(ushort));
  float* hbuf   = (float*)alloc((size_t)NN * 64 * sizeof(float));
  size_t fixed = off;

  // T2 chunk sizing: KC*8 bf16 = 1152 B per row
  long long avail = (long long)ws_size - (long long)fixed;
  int chunk = (int)(avail / (KC * 8 * sizeof(ushort)));
  if (chunk > NN) chunk = NN;
  chunk &= ~15;
  if (chunk < 16) chunk = 16;
  ushort* T2 = (ushort*)alloc((size_t)chunk * KC * 8 * sizeof(ushort));

  // ---- CSR build + weight prep ----
  hipMemsetAsync(cnt, 0, NN * sizeof(int), stream);
  hist_kernel<<<1024, 256, 0, stream>>>(dstv, cnt);
  scan_kernel<<<1, 1024, 0, stream>>>(cnt, pstart, degv);
  fillpk_kernel<<<(PKCAP + 255) / 256, 256, 0, stream>>>(pk);
  scatter_kernel<<<1024, 256, 0, stream>>>(dstv, srcv, etypes, pstart, cnt, pk);
  cpad_kernel<<<1, 512, 0, stream>>>(comp0, comp1, comp2, cpad);
  wprep_kernel<<<(KC * 64 * 8 + 255) / 256, 256, 0, stream>>>(basis0, loop0, W2_0, 64, 64);
  wprep_kernel<<<(KC * 64 * 8 + 255) / 256, 256, 0, stream>>>(basis1, loop1, W2_1, 64, 64);
  wprep_kernel<<<(KC * 16 * 8 + 255) / 256, 256, 0, stream>>>(basis2, loop2, W2_2, 8, 16);

  // ---- 3 layers, chunked over dst rows ----
  const float* bias_l[3] = {bias0, bias1, bias2};
  const ushort* w2_l[3]  = {W2_0, W2_1, W2_2};
  const float* in_l[3]   = {features, hbuf, hbuf};
  float* out_l[3]        = {hbuf, hbuf, (float*)d_out};
  const float slope_l[3] = {0.01f, 0.01f, 0.0f};

  for (int l = 0; l < 3; ++l) {
    for (int c0 = 0; c0 < NN; c0 += chunk) {
      int c1 = c0 + chunk;
      if (c1 > NN) c1 = NN;
      int rows = c1 - c0;
      int gridA = (rows + 3) / 4;                 // 1 dst per wave, 4 waves/block
      int mtiles = (rows + 15) / 16;
      int gridB = (mtiles + 3) / 4;               // 1 m-tile per wave, 4 waves/block
      agg_kernel<<<gridA, 256, 0, stream>>>(in_l[l], cpad + l * 136, pstart, degv,
                                            pk, T2, c0, c1, chunk);
      if (l < 2) {
        dense_mfma_kernel<4, 64, 64><<<gridB, 256, 0, stream>>>(
            T2, w2_l[l], bias_l[l], out_l[l], c0, c1, chunk, slope_l[l]);
      } else {
        dense_mfma_kernel<1, 16, 8><<<gridB, 256, 0, stream>>>(
            T2, w2_l[l], bias_l[l], out_l[l], c0, c1, chunk, slope_l[l]);
      }
    }
  }
}

// Round 6
// 259.156 us; speedup vs baseline: 8.0304x; 1.5792x over previous
//
#include <hip/hip_runtime.h>

#define NN 50000
#define NE 800000
#define PKCAP 950272   // >= NE + 3*NN, 4-aligned padded edge array capacity
#define KC 72          // 576/8 k-chunks

typedef __bf16 bf16x8 __attribute__((ext_vector_type(8)));
typedef float f32x4 __attribute__((ext_vector_type(4)));
typedef unsigned short ushort;
typedef unsigned int uint;

__device__ inline ushort f2bf(float x) {  // RNE float->bf16
  uint u = __builtin_bit_cast(uint, x);
  u += 0x7FFF + ((u >> 16) & 1);
  return (ushort)(u >> 16);
}
__device__ inline float bf2f(ushort u) {
  return __builtin_bit_cast(float, (uint)u << 16);
}

// ---------------- build: histogram ----------------

__global__ __launch_bounds__(256) void hist_kernel(const int* __restrict__ dstv,
                                                   int* __restrict__ cnt) {
  int i = blockIdx.x * blockDim.x + threadIdx.x;
  int stride = gridDim.x * blockDim.x;
  for (; i < NE; i += stride) atomicAdd(&cnt[dstv[i]], 1);
}

// ---------------- build: atomic segment allocator (replaces scan) ----------
// Order of segments across dsts is irrelevant; only per-dst contiguity matters.
// Wave-scan padded degrees, one atomicAdd per wave on a global counter.
__global__ __launch_bounds__(256) void alloc_kernel(int* __restrict__ cnt,
                                                    int* __restrict__ pstart,
                                                    int* __restrict__ degv,
                                                    int* __restrict__ counter) {
  int i = blockIdx.x * 256 + threadIdx.x;
  int lane = threadIdx.x & 63;
  int c = 0, pad = 0;
  if (i < NN) { c = cnt[i]; pad = (c + 3) & ~3; }
  int x = pad;
#pragma unroll
  for (int off = 1; off < 64; off <<= 1) {
    int v = __shfl_up(x, off, 64);
    if (lane >= off) x += v;
  }
  int total = __shfl(x, 63, 64);
  int base = 0;
  if (lane == 63) base = atomicAdd(counter, total);
  base = __shfl(base, 63, 64);
  if (i < NN) {
    pstart[i] = base + x - pad;
    degv[i] = c;
    cnt[i] = 0;  // reuse as scatter cursor
  }
}

__global__ __launch_bounds__(256) void fillpk_kernel(int* __restrict__ pk) {
  int i = blockIdx.x * 256 + threadIdx.x;
  if (i < PKCAP) pk[i] = (16 << 16);  // sentinel: etype 16 (zero comp row)
}

__global__ __launch_bounds__(256) void scatter_kernel(const int* __restrict__ dstv,
                                                      const int* __restrict__ srcv,
                                                      const int* __restrict__ etv,
                                                      const int* __restrict__ pstart,
                                                      int* __restrict__ cursor,
                                                      int* __restrict__ pk) {
  int i = blockIdx.x * blockDim.x + threadIdx.x;
  int stride = gridDim.x * blockDim.x;
  for (; i < NE; i += stride) {
    int d = dstv[i];
    int p = atomicAdd(&cursor[d], 1);
    pk[pstart[d] + p] = (etv[i] << 16) | srcv[i];
  }
}

// comp_pad[3][17][8]: per-layer comp with an extra zero row for the sentinel
__global__ __launch_bounds__(512) void cpad_kernel(const float* __restrict__ c0,
                                                   const float* __restrict__ c1,
                                                   const float* __restrict__ c2,
                                                   float* __restrict__ cp) {
  int t = threadIdx.x;
  if (t < 408) {
    int l = t / 136, k = t % 136;
    const float* src = (l == 0) ? c0 : ((l == 1) ? c1 : c2);
    cp[t] = (k < 128) ? src[k] : 0.f;
  }
}

// features f32 -> bf16
__global__ __launch_bounds__(256) void fbf_kernel(const float* __restrict__ f,
                                                  ushort* __restrict__ o) {
  int i = blockIdx.x * 256 + threadIdx.x;
  if (i < NN * 64 / 4) {
    float4 v = ((const float4*)f)[i];
    ushort4 u;
    u.x = f2bf(v.x); u.y = f2bf(v.y); u.z = f2bf(v.z); u.w = f2bf(v.w);
    ((ushort4*)o)[i] = u;
  }
}

// pack [basis;loop] (576 x DOUT) into chunked bf16 W2[KC][NCOLS][8]
__global__ __launch_bounds__(256) void wprep_kernel(const float* __restrict__ basis,
                                                    const float* __restrict__ loopw,
                                                    ushort* __restrict__ W2,
                                                    int DOUT, int NCOLS) {
  int idx = blockIdx.x * 256 + threadIdx.x;
  int total = KC * NCOLS * 8;
  if (idx >= total) return;
  int j = idx & 7;
  int n = (idx >> 3) % NCOLS;
  int kc = idx / (8 * NCOLS);
  int k = kc * 8 + j;
  float v = 0.f;
  if (n < DOUT) v = (k < 512) ? basis[k * DOUT + n] : loopw[(k - 512) * DOUT + n];
  W2[((size_t)kc * NCOLS + n) * 8 + j] = f2bf(v);
}

// ---------------- Phase A: per-dst basis-space aggregation (bf16 gather) ----
// One dst per wave (lane = feature). Branch-free aligned int4 edge walk with
// next-group prefetch. Writes chunked bf16 T2[kc][mloc][8]: kc 0..63 =
// deg-normalized basis coords, kc 64..71 = copy of h[d] (self-loop input).

__global__ __launch_bounds__(256) void agg_kernel(
    const ushort* __restrict__ hb,     // [NN,64] bf16
    const float* __restrict__ cpad,    // [17,8] for this layer
    const int* __restrict__ pstart,
    const int* __restrict__ degv,
    const int* __restrict__ pk,
    ushort* __restrict__ T2,           // [KC][chunk][8] bf16
    int c0, int c1, int chunk)
{
  int lane = threadIdx.x & 63;
  int d = __builtin_amdgcn_readfirstlane(c0 + ((blockIdx.x * 256 + threadIdx.x) >> 6));
  if (d >= c1) return;
  int deg = degv[d];
  int ng = (deg + 3) >> 2;
  const int4* p4 = (const int4*)(pk + pstart[d]);

  float acc[8] = {0.f, 0.f, 0.f, 0.f, 0.f, 0.f, 0.f, 0.f};
  if (ng > 0) {
    int4 pv = p4[0];
    for (int g = 0; g < ng; ++g) {
      int4 nv = pv;
      if (g + 1 < ng) nv = p4[g + 1];  // prefetch next group
      {
        int pe = pv.x;
        float hv = bf2f(hb[(size_t)(pe & 0xFFFF) * 64 + lane]);
        const float* c = cpad + (pe >> 16) * 8;
#pragma unroll
        for (int b = 0; b < 8; ++b) acc[b] = fmaf(c[b], hv, acc[b]);
      }
      {
        int pe = pv.y;
        float hv = bf2f(hb[(size_t)(pe & 0xFFFF) * 64 + lane]);
        const float* c = cpad + (pe >> 16) * 8;
#pragma unroll
        for (int b = 0; b < 8; ++b) acc[b] = fmaf(c[b], hv, acc[b]);
      }
      {
        int pe = pv.z;
        float hv = bf2f(hb[(size_t)(pe & 0xFFFF) * 64 + lane]);
        const float* c = cpad + (pe >> 16) * 8;
#pragma unroll
        for (int b = 0; b < 8; ++b) acc[b] = fmaf(c[b], hv, acc[b]);
      }
      {
        int pe = pv.w;
        float hv = bf2f(hb[(size_t)(pe & 0xFFFF) * 64 + lane]);
        const float* c = cpad + (pe >> 16) * 8;
#pragma unroll
        for (int b = 0; b < 8; ++b) acc[b] = fmaf(c[b], hv, acc[b]);
      }
      pv = nv;
    }
  }
  float inv = 1.0f / (float)(deg > 1 ? deg : 1);
  int mloc = d - c0;
  int jj = lane & 7;
  int csub = lane >> 3;
#pragma unroll
  for (int b = 0; b < 8; ++b) {
    int kc = b * 8 + csub;
    T2[((size_t)kc * chunk + mloc) * 8 + jj] = f2bf(acc[b] * inv);
  }
  // self-loop input: raw bf16 passthrough
  T2[((size_t)(64 + csub) * chunk + mloc) * 8 + jj] = hb[(size_t)d * 64 + lane];
}

// ---------------- Phase B: MFMA dense  out[m][n] = T[m] . Wcat[:,n] ----------
// Swapped operands: D = A*B with A[i=n][k] = Wcat[k][n], B[k][j=m] = T[m][k].
// kc = ks*4 + (l>>4).  D: lane holds n=(l>>4)*4+reg, m=mbase+(l&15).

template <int NT, int NCOLS, int DOUT, bool OBF>
__global__ __launch_bounds__(256) void dense_mfma_kernel(
    const ushort* __restrict__ T2,     // [KC][chunk][8] bf16
    const ushort* __restrict__ W2,     // [KC][NCOLS][8] bf16
    const float* __restrict__ bias,    // [DOUT]
    void* __restrict__ outp,           // [NN,DOUT] bf16 (OBF) or f32
    int c0, int c1, int chunk, float slope)
{
  int tid = threadIdx.x;
  int gw = blockIdx.x * 4 + (tid >> 6);   // global wave id = m-tile id
  int rows = c1 - c0;
  int mbase = gw * 16;
  if (mbase >= rows) return;
  int l = tid & 63;
  int q = l >> 4;
  int r = l & 15;

  f32x4 acc[NT];
#pragma unroll
  for (int nt = 0; nt < NT; ++nt) acc[nt] = f32x4{0.f, 0.f, 0.f, 0.f};

#pragma unroll 2
  for (int ks = 0; ks < 18; ++ks) {
    int kc = ks * 4 + q;
    bf16x8 bfrag = *(const bf16x8*)(T2 + ((size_t)kc * chunk + mbase + r) * 8);
#pragma unroll
    for (int nt = 0; nt < NT; ++nt) {
      bf16x8 afrag = *(const bf16x8*)(W2 + ((size_t)kc * NCOLS + nt * 16 + r) * 8);
      acc[nt] = __builtin_amdgcn_mfma_f32_16x16x32_bf16(afrag, bfrag, acc[nt], 0, 0, 0);
    }
  }

  int m = c0 + mbase + r;
  if (m >= c1) return;
#pragma unroll
  for (int nt = 0; nt < NT; ++nt) {
    int nb = nt * 16 + q * 4;
    if (nb < DOUT) {
      float4 bv = *(const float4*)(bias + nb);
      float v0 = acc[nt][0] + bv.x;
      float v1 = acc[nt][1] + bv.y;
      float v2 = acc[nt][2] + bv.z;
      float v3 = acc[nt][3] + bv.w;
      v0 = v0 > 0.f ? v0 : slope * v0;
      v1 = v1 > 0.f ? v1 : slope * v1;
      v2 = v2 > 0.f ? v2 : slope * v2;
      v3 = v3 > 0.f ? v3 : slope * v3;
      if (OBF) {
        ushort4 u;
        u.x = f2bf(v0); u.y = f2bf(v1); u.z = f2bf(v2); u.w = f2bf(v3);
        *(ushort4*)((ushort*)outp + (size_t)m * DOUT + nb) = u;
      } else {
        *(float4*)((float*)outp + (size_t)m * DOUT + nb) = float4{v0, v1, v2, v3};
      }
    }
  }
}

// ---------------- launch ----------------

extern "C" void kernel_launch(void* const* d_in, const int* in_sizes, int n_in,
                              void* d_out, int out_size, void* d_ws, size_t ws_size,
                              hipStream_t stream) {
  const float* features = (const float*)d_in[0];
  const float* basis0   = (const float*)d_in[2];
  const float* comp0    = (const float*)d_in[3];
  const float* loop0    = (const float*)d_in[4];
  const float* bias0    = (const float*)d_in[5];
  const float* basis1   = (const float*)d_in[6];
  const float* comp1    = (const float*)d_in[7];
  const float* loop1    = (const float*)d_in[8];
  const float* bias1    = (const float*)d_in[9];
  const float* basis2   = (const float*)d_in[10];
  const float* comp2    = (const float*)d_in[11];
  const float* loop2    = (const float*)d_in[12];
  const float* bias2    = (const float*)d_in[13];
  const int* etypes     = (const int*)d_in[14];
  const int* srcv       = (const int*)d_in[15];
  const int* dstv       = (const int*)d_in[16];

  char* ws = (char*)d_ws;
  size_t off = 0;
  auto alloc = [&](size_t bytes) {
    void* p = ws + off;
    off += (bytes + 255) & ~(size_t)255;
    return p;
  };
  int* pstart   = (int*)alloc(NN * sizeof(int));
  int* degv     = (int*)alloc(NN * sizeof(int));
  int* cnt      = (int*)alloc((NN + 64) * sizeof(int));  // cnt[NN] = alloc counter
  int* pk       = (int*)alloc((size_t)PKCAP * sizeof(int));
  float* cpad   = (float*)alloc(3 * 136 * sizeof(float));
  ushort* W2_0  = (ushort*)alloc((size_t)KC * 64 * 8 * sizeof(ushort));
  ushort* W2_1  = (ushort*)alloc((size_t)KC * 64 * 8 * sizeof(ushort));
  ushort* W2_2  = (ushort*)alloc((size_t)KC * 16 * 8 * sizeof(ushort));
  ushort* fbf   = (ushort*)alloc((size_t)NN * 64 * sizeof(ushort));
  ushort* hA    = (ushort*)alloc((size_t)NN * 64 * sizeof(ushort));
  ushort* hB    = (ushort*)alloc((size_t)NN * 64 * sizeof(ushort));
  size_t fixed = off;

  // T2 chunk sizing: KC*8 bf16 = 1152 B per row
  long long avail = (long long)ws_size - (long long)fixed;
  int chunk = (int)(avail / (KC * 8 * sizeof(ushort)));
  if (chunk > NN) chunk = NN;
  chunk &= ~15;
  if (chunk < 16) chunk = 16;
  ushort* T2 = (ushort*)alloc((size_t)chunk * KC * 8 * sizeof(ushort));

  // ---- build + weight prep ----
  hipMemsetAsync(cnt, 0, (NN + 1) * sizeof(int), stream);
  hist_kernel<<<1024, 256, 0, stream>>>(dstv, cnt);
  alloc_kernel<<<(NN + 255) / 256, 256, 0, stream>>>(cnt, pstart, degv, cnt + NN);
  fillpk_kernel<<<(PKCAP + 255) / 256, 256, 0, stream>>>(pk);
  scatter_kernel<<<1024, 256, 0, stream>>>(dstv, srcv, etypes, pstart, cnt, pk);
  cpad_kernel<<<1, 512, 0, stream>>>(comp0, comp1, comp2, cpad);
  fbf_kernel<<<(NN * 64 / 4 + 255) / 256, 256, 0, stream>>>(features, fbf);
  wprep_kernel<<<(KC * 64 * 8 + 255) / 256, 256, 0, stream>>>(basis0, loop0, W2_0, 64, 64);
  wprep_kernel<<<(KC * 64 * 8 + 255) / 256, 256, 0, stream>>>(basis1, loop1, W2_1, 64, 64);
  wprep_kernel<<<(KC * 16 * 8 + 255) / 256, 256, 0, stream>>>(basis2, loop2, W2_2, 8, 16);

  // ---- 3 layers, chunked over dst rows ----
  const float* bias_l[3]  = {bias0, bias1, bias2};
  const ushort* w2_l[3]   = {W2_0, W2_1, W2_2};
  const ushort* in_l[3]   = {fbf, hA, hB};
  void* out_l[3]          = {hA, hB, d_out};
  const float slope_l[3]  = {0.01f, 0.01f, 0.0f};

  for (int l = 0; l < 3; ++l) {
    for (int c0 = 0; c0 < NN; c0 += chunk) {
      int c1 = c0 + chunk;
      if (c1 > NN) c1 = NN;
      int rows = c1 - c0;
      int gridA = (rows + 3) / 4;                 // 1 dst per wave, 4 waves/block
      int mtiles = (rows + 15) / 16;
      int gridB = (mtiles + 3) / 4;               // 1 m-tile per wave, 4 waves/block
      agg_kernel<<<gridA, 256, 0, stream>>>(in_l[l], cpad + l * 136, pstart, degv,
                                            pk, T2, c0, c1, chunk);
      if (l < 2) {
        dense_mfma_kernel<4, 64, 64, true><<<gridB, 256, 0, stream>>>(
            T2, w2_l[l], bias_l[l], out_l[l], c0, c1, chunk, slope_l[l]);
      } else {
        dense_mfma_kernel<1, 16, 8, false><<<gridB, 256, 0, stream>>>(
            T2, w2_l[l], bias_l[l], out_l[l], c0, c1, chunk, slope_l[l]);
      }
    }
  }
}

// Round 7
// 208.585 us; speedup vs baseline: 9.9773x; 1.2424x over previous
//
#include <hip/hip_runtime.h>

#define NN 50000
#define NE 800000
#define CAP 128        // per-dst edge bucket capacity (Poisson(16) max ~45)
#define KC 72          // 576/8 k-chunks

typedef __bf16 bf16x8 __attribute__((ext_vector_type(8)));
typedef float f32x4 __attribute__((ext_vector_type(4)));
typedef unsigned short ushort;
typedef unsigned int uint;

__device__ inline ushort f2bf(float x) {  // RNE float->bf16
  uint u = __builtin_bit_cast(uint, x);
  u += 0x7FFF + ((u >> 16) & 1);
  return (ushort)(u >> 16);
}
__device__ inline float bf2f(ushort u) {
  return __builtin_bit_cast(float, (uint)u << 16);
}

// ---------------- build: one-pass bucketed scatter ----------------
// pk[d*CAP + p] = (etype<<16)|src, p = atomicAdd(cursor[d]). cursor ends as degree.
__global__ __launch_bounds__(256) void scatter_kernel(const int4* __restrict__ dst4,
                                                      const int4* __restrict__ src4,
                                                      const int4* __restrict__ et4,
                                                      int* __restrict__ cursor,
                                                      int* __restrict__ pk) {
  int i = blockIdx.x * 256 + threadIdx.x;
  if (i >= NE / 4) return;
  int4 d = dst4[i];
  int4 s = src4[i];
  int4 e = et4[i];
  int p0 = atomicAdd(&cursor[d.x], 1);
  int p1 = atomicAdd(&cursor[d.y], 1);
  int p2 = atomicAdd(&cursor[d.z], 1);
  int p3 = atomicAdd(&cursor[d.w], 1);
  if (p0 < CAP) pk[d.x * CAP + p0] = (e.x << 16) | s.x;
  if (p1 < CAP) pk[d.y * CAP + p1] = (e.y << 16) | s.y;
  if (p2 < CAP) pk[d.z * CAP + p2] = (e.z << 16) | s.z;
  if (p3 < CAP) pk[d.w * CAP + p3] = (e.w << 16) | s.w;
}

// ---------------- merged prep: features->bf16 + 3x weight pack ----------------
// blocks [0,3125): fbf; [3125,3269): W0; [3269,3413): W1; [3413,3449): W2
__device__ inline void wprep_body(const float* __restrict__ basis,
                                  const float* __restrict__ loopw,
                                  ushort* __restrict__ W2, int DOUT, int NCOLS,
                                  int idx) {
  int total = KC * NCOLS * 8;
  if (idx >= total) return;
  int j = idx & 7;
  int n = (idx >> 3) % NCOLS;
  int kc = idx / (8 * NCOLS);
  int k = kc * 8 + j;
  float v = 0.f;
  if (n < DOUT) v = (k < 512) ? basis[k * DOUT + n] : loopw[(k - 512) * DOUT + n];
  W2[((size_t)kc * NCOLS + n) * 8 + j] = f2bf(v);
}

__global__ __launch_bounds__(256) void prep_kernel(
    const float* __restrict__ f, ushort* __restrict__ fb,
    const float* __restrict__ b0, const float* __restrict__ l0, ushort* __restrict__ W0,
    const float* __restrict__ b1, const float* __restrict__ l1, ushort* __restrict__ W1,
    const float* __restrict__ b2, const float* __restrict__ l2, ushort* __restrict__ W2) {
  int blk = blockIdx.x;
  int tid = threadIdx.x;
  if (blk < 3125) {
    int i = blk * 256 + tid;  // ushort4 granules: NN*64/4 = 800000
    if (i < NN * 16) {
      float4 v = ((const float4*)f)[i];
      ushort4 u;
      u.x = f2bf(v.x); u.y = f2bf(v.y); u.z = f2bf(v.z); u.w = f2bf(v.w);
      ((ushort4*)fb)[i] = u;
    }
  } else if (blk < 3269) {
    wprep_body(b0, l0, W0, 64, 64, (blk - 3125) * 256 + tid);
  } else if (blk < 3413) {
    wprep_body(b1, l1, W1, 64, 64, (blk - 3269) * 256 + tid);
  } else {
    wprep_body(b2, l2, W2, 8, 16, (blk - 3413) * 256 + tid);
  }
}

// ---------------- Phase A: per-dst basis-space aggregation (bf16 gather) ----
// One dst per wave (lane = feature). deg>>2 full int4 groups with next-group
// prefetch + <=3 scalar-tail edges (wave-uniform branch). comp read via s_load.
// Writes chunked bf16 T2[kc][mloc][8]: kc 0..63 = deg-normalized basis coords,
// kc 64..71 = copy of h[d] (self-loop input).

__global__ __launch_bounds__(256) void agg_kernel(
    const ushort* __restrict__ hb,     // [NN,64] bf16
    const float* __restrict__ comp,    // [16,8] f32
    const int* __restrict__ degv,
    const int* __restrict__ pk,        // [NN,CAP]
    ushort* __restrict__ T2,           // [KC][chunk][8] bf16
    int c0, int c1, int chunk)
{
  int lane = threadIdx.x & 63;
  int d = __builtin_amdgcn_readfirstlane(c0 + ((blockIdx.x * 256 + threadIdx.x) >> 6));
  if (d >= c1) return;
  int deg = degv[d];
  if (deg > CAP) deg = CAP;
  const int* pb = pk + (size_t)d * CAP;
  const int4* p4 = (const int4*)pb;
  int ng = deg >> 2;

  float acc[8] = {0.f, 0.f, 0.f, 0.f, 0.f, 0.f, 0.f, 0.f};
  if (ng > 0) {
    int4 pv = p4[0];
    for (int g = 0; g < ng; ++g) {
      int4 nv = pv;
      if (g + 1 < ng) nv = p4[g + 1];  // prefetch next group
      {
        int pe = pv.x;
        float hv = bf2f(hb[(size_t)(pe & 0xFFFF) * 64 + lane]);
        const float* c = comp + (pe >> 16) * 8;
#pragma unroll
        for (int b = 0; b < 8; ++b) acc[b] = fmaf(c[b], hv, acc[b]);
      }
      {
        int pe = pv.y;
        float hv = bf2f(hb[(size_t)(pe & 0xFFFF) * 64 + lane]);
        const float* c = comp + (pe >> 16) * 8;
#pragma unroll
        for (int b = 0; b < 8; ++b) acc[b] = fmaf(c[b], hv, acc[b]);
      }
      {
        int pe = pv.z;
        float hv = bf2f(hb[(size_t)(pe & 0xFFFF) * 64 + lane]);
        const float* c = comp + (pe >> 16) * 8;
#pragma unroll
        for (int b = 0; b < 8; ++b) acc[b] = fmaf(c[b], hv, acc[b]);
      }
      {
        int pe = pv.w;
        float hv = bf2f(hb[(size_t)(pe & 0xFFFF) * 64 + lane]);
        const float* c = comp + (pe >> 16) * 8;
#pragma unroll
        for (int b = 0; b < 8; ++b) acc[b] = fmaf(c[b], hv, acc[b]);
      }
      pv = nv;
    }
  }
  for (int j = deg & ~3; j < deg; ++j) {  // tail (<=3, wave-uniform)
    int pe = __builtin_amdgcn_readfirstlane(pb[j]);
    float hv = bf2f(hb[(size_t)(pe & 0xFFFF) * 64 + lane]);
    const float* c = comp + (pe >> 16) * 8;
#pragma unroll
    for (int b = 0; b < 8; ++b) acc[b] = fmaf(c[b], hv, acc[b]);
  }

  float inv = 1.0f / (float)(deg > 1 ? deg : 1);
  int mloc = d - c0;
  int jj = lane & 7;
  int csub = lane >> 3;
#pragma unroll
  for (int b = 0; b < 8; ++b) {
    int kc = b * 8 + csub;
    T2[((size_t)kc * chunk + mloc) * 8 + jj] = f2bf(acc[b] * inv);
  }
  // self-loop input: raw bf16 passthrough
  T2[((size_t)(64 + csub) * chunk + mloc) * 8 + jj] = hb[(size_t)d * 64 + lane];
}

// ---------------- Phase B: MFMA dense  out[m][n] = T[m] . Wcat[:,n] ----------
// Swapped operands: D = A*B with A[i=n][k] = Wcat[k][n], B[k][j=m] = T[m][k].
// kc = ks*4 + (l>>4).  D: lane holds n=(l>>4)*4+reg, m=mbase+(l&15).

template <int NT, int NCOLS, int DOUT, bool OBF>
__global__ __launch_bounds__(256) void dense_mfma_kernel(
    const ushort* __restrict__ T2,     // [KC][chunk][8] bf16
    const ushort* __restrict__ W2,     // [KC][NCOLS][8] bf16
    const float* __restrict__ bias,    // [DOUT]
    void* __restrict__ outp,           // [NN,DOUT] bf16 (OBF) or f32
    int c0, int c1, int chunk, float slope)
{
  int tid = threadIdx.x;
  int gw = blockIdx.x * 4 + (tid >> 6);   // global wave id = m-tile id
  int rows = c1 - c0;
  int mbase = gw * 16;
  if (mbase >= rows) return;
  int l = tid & 63;
  int q = l >> 4;
  int r = l & 15;

  f32x4 acc[NT];
#pragma unroll
  for (int nt = 0; nt < NT; ++nt) acc[nt] = f32x4{0.f, 0.f, 0.f, 0.f};

#pragma unroll 2
  for (int ks = 0; ks < 18; ++ks) {
    int kc = ks * 4 + q;
    bf16x8 bfrag = *(const bf16x8*)(T2 + ((size_t)kc * chunk + mbase + r) * 8);
#pragma unroll
    for (int nt = 0; nt < NT; ++nt) {
      bf16x8 afrag = *(const bf16x8*)(W2 + ((size_t)kc * NCOLS + nt * 16 + r) * 8);
      acc[nt] = __builtin_amdgcn_mfma_f32_16x16x32_bf16(afrag, bfrag, acc[nt], 0, 0, 0);
    }
  }

  int m = c0 + mbase + r;
  if (m >= c1) return;
#pragma unroll
  for (int nt = 0; nt < NT; ++nt) {
    int nb = nt * 16 + q * 4;
    if (nb < DOUT) {
      float4 bv = *(const float4*)(bias + nb);
      float v0 = acc[nt][0] + bv.x;
      float v1 = acc[nt][1] + bv.y;
      float v2 = acc[nt][2] + bv.z;
      float v3 = acc[nt][3] + bv.w;
      v0 = v0 > 0.f ? v0 : slope * v0;
      v1 = v1 > 0.f ? v1 : slope * v1;
      v2 = v2 > 0.f ? v2 : slope * v2;
      v3 = v3 > 0.f ? v3 : slope * v3;
      if (OBF) {
        ushort4 u;
        u.x = f2bf(v0); u.y = f2bf(v1); u.z = f2bf(v2); u.w = f2bf(v3);
        *(ushort4*)((ushort*)outp + (size_t)m * DOUT + nb) = u;
      } else {
        *(float4*)((float*)outp + (size_t)m * DOUT + nb) = float4{v0, v1, v2, v3};
      }
    }
  }
}

// ---------------- launch ----------------

extern "C" void kernel_launch(void* const* d_in, const int* in_sizes, int n_in,
                              void* d_out, int out_size, void* d_ws, size_t ws_size,
                              hipStream_t stream) {
  const float* features = (const float*)d_in[0];
  const float* basis0   = (const float*)d_in[2];
  const float* comp0    = (const float*)d_in[3];
  const float* loop0    = (const float*)d_in[4];
  const float* bias0    = (const float*)d_in[5];
  const float* basis1   = (const float*)d_in[6];
  const float* comp1    = (const float*)d_in[7];
  const float* loop1    = (const float*)d_in[8];
  const float* bias1    = (const float*)d_in[9];
  const float* basis2   = (const float*)d_in[10];
  const float* comp2    = (const float*)d_in[11];
  const float* loop2    = (const float*)d_in[12];
  const float* bias2    = (const float*)d_in[13];
  const int* etypes     = (const int*)d_in[14];
  const int* srcv       = (const int*)d_in[15];
  const int* dstv       = (const int*)d_in[16];

  char* ws = (char*)d_ws;
  size_t off = 0;
  auto alloc = [&](size_t bytes) {
    void* p = ws + off;
    off += (bytes + 255) & ~(size_t)255;
    return p;
  };
  int* cnt      = (int*)alloc(NN * sizeof(int));          // scatter cursor -> degree
  int* pk       = (int*)alloc((size_t)NN * CAP * sizeof(int));
  ushort* W2_0  = (ushort*)alloc((size_t)KC * 64 * 8 * sizeof(ushort));
  ushort* W2_1  = (ushort*)alloc((size_t)KC * 64 * 8 * sizeof(ushort));
  ushort* W2_2  = (ushort*)alloc((size_t)KC * 16 * 8 * sizeof(ushort));
  ushort* fbf   = (ushort*)alloc((size_t)NN * 64 * sizeof(ushort));
  ushort* hA    = (ushort*)alloc((size_t)NN * 64 * sizeof(ushort));
  ushort* hB    = (ushort*)alloc((size_t)NN * 64 * sizeof(ushort));
  size_t fixed = off;

  // T2 chunk sizing: KC*8 bf16 = 1152 B per row
  long long avail = (long long)ws_size - (long long)fixed;
  int chunk = (int)(avail / (KC * 8 * sizeof(ushort)));
  if (chunk > NN) chunk = NN;
  chunk &= ~15;
  if (chunk < 16) chunk = 16;
  ushort* T2 = (ushort*)alloc((size_t)chunk * KC * 8 * sizeof(ushort));

  // ---- build + prep (3 dispatches total) ----
  hipMemsetAsync(cnt, 0, NN * sizeof(int), stream);
  scatter_kernel<<<(NE / 4 + 255) / 256, 256, 0, stream>>>(
      (const int4*)dstv, (const int4*)srcv, (const int4*)etypes, cnt, pk);
  prep_kernel<<<3449, 256, 0, stream>>>(features, fbf,
                                        basis0, loop0, W2_0,
                                        basis1, loop1, W2_1,
                                        basis2, loop2, W2_2);

  // ---- 3 layers, chunked over dst rows ----
  const float* bias_l[3]  = {bias0, bias1, bias2};
  const float* comp_l[3]  = {comp0, comp1, comp2};
  const ushort* w2_l[3]   = {W2_0, W2_1, W2_2};
  const ushort* in_l[3]   = {fbf, hA, hB};
  void* out_l[3]          = {hA, hB, d_out};
  const float slope_l[3]  = {0.01f, 0.01f, 0.0f};

  for (int l = 0; l < 3; ++l) {
    for (int c0 = 0; c0 < NN; c0 += chunk) {
      int c1 = c0 + chunk;
      if (c1 > NN) c1 = NN;
      int rows = c1 - c0;
      int gridA = (rows + 3) / 4;                 // 1 dst per wave, 4 waves/block
      int mtiles = (rows + 15) / 16;
      int gridB = (mtiles + 3) / 4;               // 1 m-tile per wave, 4 waves/block
      agg_kernel<<<gridA, 256, 0, stream>>>(in_l[l], comp_l[l], cnt, pk,
                                            T2, c0, c1, chunk);
      if (l < 2) {
        dense_mfma_kernel<4, 64, 64, true><<<gridB, 256, 0, stream>>>(
            T2, w2_l[l], bias_l[l], out_l[l], c0, c1, chunk, slope_l[l]);
      } else {
        dense_mfma_kernel<1, 16, 8, false><<<gridB, 256, 0, stream>>>(
            T2, w2_l[l], bias_l[l], out_l[l], c0, c1, chunk, slope_l[l]);
      }
    }
  }
}

// Round 8
// 171.380 us; speedup vs baseline: 12.1433x; 1.2171x over previous
//
#include <hip/hip_runtime.h>

#define NN 50000
#define NE 800000
#define CAP 64         // per-dst bucket capacity; Poisson(16) P(>64) ~ 1e-18
#define KC 72          // 576/8 k-chunks

typedef __bf16 bf16x8 __attribute__((ext_vector_type(8)));
typedef float f32x4 __attribute__((ext_vector_type(4)));
typedef unsigned short ushort;
typedef unsigned int uint;

__device__ inline ushort f2bf(float x) {  // RNE float->bf16
  uint u = __builtin_bit_cast(uint, x);
  u += 0x7FFF + ((u >> 16) & 1);
  return (ushort)(u >> 16);
}
__device__ inline float bf2f(ushort u) {
  return __builtin_bit_cast(float, (uint)u << 16);
}

// ---------------- merged build: scatter + features->bf16 + weight pack -------
// blocks [0,3125): scatter (1 edge/thread, max TLP for atomic latency)
// blocks [3125,6250): features f32->bf16
// blocks [6250,6394): W0 pack; [6394,6538): W1; [6538,6574): W2
// The BW-streaming blocks hide the atomic waves' L2 round-trip latency.

__device__ inline void wprep_body(const float* __restrict__ basis,
                                  const float* __restrict__ loopw,
                                  ushort* __restrict__ W2, int DOUT, int NCOLS,
                                  int idx) {
  int total = KC * NCOLS * 8;
  if (idx >= total) return;
  int j = idx & 7;
  int n = (idx >> 3) % NCOLS;
  int kc = idx / (8 * NCOLS);
  int k = kc * 8 + j;
  float v = 0.f;
  if (n < DOUT) v = (k < 512) ? basis[k * DOUT + n] : loopw[(k - 512) * DOUT + n];
  W2[((size_t)kc * NCOLS + n) * 8 + j] = f2bf(v);
}

__global__ __launch_bounds__(256) void build_kernel(
    const int* __restrict__ dstv, const int* __restrict__ srcv,
    const int* __restrict__ etv, int* __restrict__ cursor, int* __restrict__ pk,
    const float* __restrict__ f, ushort* __restrict__ fb,
    const float* __restrict__ b0, const float* __restrict__ l0, ushort* __restrict__ W0,
    const float* __restrict__ b1, const float* __restrict__ l1, ushort* __restrict__ W1,
    const float* __restrict__ b2, const float* __restrict__ l2, ushort* __restrict__ W2) {
  int blk = blockIdx.x;
  int tid = threadIdx.x;
  if (blk < 3125) {
    int i = blk * 256 + tid;  // NE = 3125*256 exactly
    int d = dstv[i];
    int p = atomicAdd(&cursor[d], 1);
    if (p < CAP) pk[d * CAP + p] = (etv[i] << 16) | srcv[i];
  } else if (blk < 6250) {
    int i = (blk - 3125) * 256 + tid;  // NN*16 = 800000 ushort4 granules
    float4 v = ((const float4*)f)[i];
    ushort4 u;
    u.x = f2bf(v.x); u.y = f2bf(v.y); u.z = f2bf(v.z); u.w = f2bf(v.w);
    ((ushort4*)fb)[i] = u;
  } else if (blk < 6394) {
    wprep_body(b0, l0, W0, 64, 64, (blk - 6250) * 256 + tid);
  } else if (blk < 6538) {
    wprep_body(b1, l1, W1, 64, 64, (blk - 6394) * 256 + tid);
  } else {
    wprep_body(b2, l2, W2, 8, 16, (blk - 6538) * 256 + tid);
  }
}

// ---------------- fused layer: agg (16 waves, 1 dst each) + MFMA dense -------
// LDS X in chunked layout [kc][m][8] bf16: dense B-frag read is 16B/lane with
// lanes 0-15 spanning 256B contiguous per kc-plane -> conflict-free.
// Dense (waves 0..3): out[m][n] = X-row(m) . Wcat[:,n] via swapped-operand
// mfma_16x16x32_bf16: A=W2[kc][n][8], B=X[kc][m][8], D: n=q*4+reg, m=r.

template <int DOUT, int NCOLS, bool OBF>
__global__ __launch_bounds__(1024, 8) void layer_kernel(
    const ushort* __restrict__ hb,     // [NN,64] bf16
    const float* __restrict__ comp,    // [16,8] f32
    const int* __restrict__ degv,
    const int* __restrict__ pk,        // [NN,CAP]
    const ushort* __restrict__ W2,     // [KC][NCOLS][8] bf16
    const float* __restrict__ bias,    // [DOUT]
    void* __restrict__ outp,           // [NN,DOUT] bf16 (OBF) or f32
    float slope)
{
  __shared__ ushort X[KC][16][8];  // 18432 B
  int tid = threadIdx.x;
  int wave = tid >> 6;
  int lane = tid & 63;
  int dbase = blockIdx.x * 16;     // grid 3125 * 16 = NN exactly
  int d = __builtin_amdgcn_readfirstlane(dbase + wave);

  // ---- Phase A: aggregate this wave's dst into basis space ----
  int deg = degv[d];
  int dw = deg > CAP ? CAP : deg;
  const int* pb = pk + (size_t)d * CAP;
  const int4* p4 = (const int4*)pb;
  int ng = dw >> 2;

  float acc[8] = {0.f, 0.f, 0.f, 0.f, 0.f, 0.f, 0.f, 0.f};
  if (ng > 0) {
    int4 pv = p4[0];
    for (int g = 0; g < ng; ++g) {
      int4 nv = pv;
      if (g + 1 < ng) nv = p4[g + 1];  // prefetch next group
      {
        int pe = __builtin_amdgcn_readfirstlane(pv.x);
        float hv = bf2f(hb[(size_t)(pe & 0xFFFF) * 64 + lane]);
        const float* c = comp + (pe >> 16) * 8;
#pragma unroll
        for (int b = 0; b < 8; ++b) acc[b] = fmaf(c[b], hv, acc[b]);
      }
      {
        int pe = __builtin_amdgcn_readfirstlane(pv.y);
        float hv = bf2f(hb[(size_t)(pe & 0xFFFF) * 64 + lane]);
        const float* c = comp + (pe >> 16) * 8;
#pragma unroll
        for (int b = 0; b < 8; ++b) acc[b] = fmaf(c[b], hv, acc[b]);
      }
      {
        int pe = __builtin_amdgcn_readfirstlane(pv.z);
        float hv = bf2f(hb[(size_t)(pe & 0xFFFF) * 64 + lane]);
        const float* c = comp + (pe >> 16) * 8;
#pragma unroll
        for (int b = 0; b < 8; ++b) acc[b] = fmaf(c[b], hv, acc[b]);
      }
      {
        int pe = __builtin_amdgcn_readfirstlane(pv.w);
        float hv = bf2f(hb[(size_t)(pe & 0xFFFF) * 64 + lane]);
        const float* c = comp + (pe >> 16) * 8;
#pragma unroll
        for (int b = 0; b < 8; ++b) acc[b] = fmaf(c[b], hv, acc[b]);
      }
      pv = nv;
    }
  }
  for (int j = dw & ~3; j < dw; ++j) {  // tail (<=3, wave-uniform)
    int pe = __builtin_amdgcn_readfirstlane(pb[j]);
    float hv = bf2f(hb[(size_t)(pe & 0xFFFF) * 64 + lane]);
    const float* c = comp + (pe >> 16) * 8;
#pragma unroll
    for (int b = 0; b < 8; ++b) acc[b] = fmaf(c[b], hv, acc[b]);
  }

  float inv = 1.0f / (float)(deg > 1 ? deg : 1);
  int jj = lane & 7;
  int csub = lane >> 3;
#pragma unroll
  for (int b = 0; b < 8; ++b) X[b * 8 + csub][wave][jj] = f2bf(acc[b] * inv);
  X[64 + csub][wave][jj] = hb[(size_t)d * 64 + lane];  // self-loop input
  __syncthreads();

  // ---- Phase B: MFMA dense (waves 0..3 for DOUT=64, wave 0 for DOUT=8) ----
  if (wave < (DOUT == 64 ? 4 : 1)) {
    int q = lane >> 4;
    int r = lane & 15;
    f32x4 acc2 = {0.f, 0.f, 0.f, 0.f};
#pragma unroll
    for (int ks = 0; ks < 18; ++ks) {
      int kc = ks * 4 + q;
      bf16x8 bfrag = *(const bf16x8*)&X[kc][r][0];
      bf16x8 afrag = *(const bf16x8*)(W2 + ((size_t)kc * NCOLS + wave * 16 + r) * 8);
      acc2 = __builtin_amdgcn_mfma_f32_16x16x32_bf16(afrag, bfrag, acc2, 0, 0, 0);
    }
    int m = dbase + r;
    int nb = wave * 16 + q * 4;
    if (nb < DOUT) {
      float4 bv = *(const float4*)(bias + nb);
      float v0 = acc2[0] + bv.x;
      float v1 = acc2[1] + bv.y;
      float v2 = acc2[2] + bv.z;
      float v3 = acc2[3] + bv.w;
      v0 = v0 > 0.f ? v0 : slope * v0;
      v1 = v1 > 0.f ? v1 : slope * v1;
      v2 = v2 > 0.f ? v2 : slope * v2;
      v3 = v3 > 0.f ? v3 : slope * v3;
      if (OBF) {
        ushort4 u;
        u.x = f2bf(v0); u.y = f2bf(v1); u.z = f2bf(v2); u.w = f2bf(v3);
        *(ushort4*)((ushort*)outp + (size_t)m * DOUT + nb) = u;
      } else {
        *(float4*)((float*)outp + (size_t)m * DOUT + nb) = float4{v0, v1, v2, v3};
      }
    }
  }
}

// ---------------- launch ----------------

extern "C" void kernel_launch(void* const* d_in, const int* in_sizes, int n_in,
                              void* d_out, int out_size, void* d_ws, size_t ws_size,
                              hipStream_t stream) {
  const float* features = (const float*)d_in[0];
  const float* basis0   = (const float*)d_in[2];
  const float* comp0    = (const float*)d_in[3];
  const float* loop0    = (const float*)d_in[4];
  const float* bias0    = (const float*)d_in[5];
  const float* basis1   = (const float*)d_in[6];
  const float* comp1    = (const float*)d_in[7];
  const float* loop1    = (const float*)d_in[8];
  const float* bias1    = (const float*)d_in[9];
  const float* basis2   = (const float*)d_in[10];
  const float* comp2    = (const float*)d_in[11];
  const float* loop2    = (const float*)d_in[12];
  const float* bias2    = (const float*)d_in[13];
  const int* etypes     = (const int*)d_in[14];
  const int* srcv       = (const int*)d_in[15];
  const int* dstv       = (const int*)d_in[16];

  char* ws = (char*)d_ws;
  size_t off = 0;
  auto alloc = [&](size_t bytes) {
    void* p = ws + off;
    off += (bytes + 255) & ~(size_t)255;
    return p;
  };
  int* cnt      = (int*)alloc(NN * sizeof(int));          // cursor -> degree
  int* pk       = (int*)alloc((size_t)NN * CAP * sizeof(int));
  ushort* W2_0  = (ushort*)alloc((size_t)KC * 64 * 8 * sizeof(ushort));
  ushort* W2_1  = (ushort*)alloc((size_t)KC * 64 * 8 * sizeof(ushort));
  ushort* W2_2  = (ushort*)alloc((size_t)KC * 16 * 8 * sizeof(ushort));
  ushort* fbf   = (ushort*)alloc((size_t)NN * 64 * sizeof(ushort));
  ushort* hA    = (ushort*)alloc((size_t)NN * 64 * sizeof(ushort));
  ushort* hB    = (ushort*)alloc((size_t)NN * 64 * sizeof(ushort));

  hipMemsetAsync(cnt, 0, NN * sizeof(int), stream);
  build_kernel<<<6574, 256, 0, stream>>>(dstv, srcv, etypes, cnt, pk,
                                         features, fbf,
                                         basis0, loop0, W2_0,
                                         basis1, loop1, W2_1,
                                         basis2, loop2, W2_2);

  layer_kernel<64, 64, true><<<3125, 1024, 0, stream>>>(
      fbf, comp0, cnt, pk, W2_0, bias0, hA, 0.01f);
  layer_kernel<64, 64, true><<<3125, 1024, 0, stream>>>(
      hA, comp1, cnt, pk, W2_1, bias1, hB, 0.01f);
  layer_kernel<8, 16, false><<<3125, 1024, 0, stream>>>(
      hB, comp2, cnt, pk, W2_2, bias2, d_out, 0.0f);
}